// Round 12
// baseline (410.689 us; speedup 1.0000x reference)
//
#include <hip/hip_runtime.h>

// CausalSelfAttention: B=2, S=2048, H=2048, NH=16, HD=128. f32 in/out, bf16 MFMA inside.
// R19b = R19 resubmitted verbatim after an infra container failure (no kernel
// defect found on audit: uniform barriers, bounds-checked staging, wave-uniform
// gl2lds dest, FIFO-correct vmcnt counts, frozen-verified GEMM/converts).
// R19 = R14-frozen GEMM + R18 fused converts + attn sync-thinning:
//   - 2 tiles per sync step (16KB chunk, dbuf 32KB LDS) -> 66 steps, half the barriers
//   - grid 1024 = one 64-row q-block per block -> 4 blocks/CU (launch_bounds(256,4)),
//     3 co-resident blocks fill every barrier/wait pocket
//   - heavy-first q ordering within each XCD (q=31 launches first, backfill absorbs tail)
//   - each wave owns its full strip -> no cross-wave merge, simpler epilogue (R9 form)
// Staging/compute/mask primitives verbatim from verified R17 body.

using bf16x8 = __attribute__((ext_vector_type(8))) short;
using bf16x4 = __attribute__((ext_vector_type(4))) short;
using f32x4  = __attribute__((ext_vector_type(4))) float;

#define S_LEN 2048
#define NHEAD 16
#define HDIM  128
#define HID   2048

__device__ __forceinline__ unsigned short f2bf(float f) {
    unsigned int u = __float_as_uint(f);
    u += 0x7fffu + ((u >> 16) & 1u);   // round-to-nearest-even
    return (unsigned short)(u >> 16);
}
__device__ __forceinline__ void gl2lds16(const void* g, void* l) {
    __builtin_amdgcn_global_load_lds(
        (const __attribute__((address_space(1))) void*)g,
        (__attribute__((address_space(3))) void*)l, 16, 0, 0);
}

// 16x16x16 bf16 MFMA, device-guarded (host pass must not reference the builtin).
__device__ __forceinline__ f32x4 pv_mfma(bf16x4 a, bf16x4 b, f32x4 c) {
#if defined(__HIP_DEVICE_COMPILE__)
#if __has_builtin(__builtin_amdgcn_mfma_f32_16x16x16bf16_1k)
    return __builtin_amdgcn_mfma_f32_16x16x16bf16_1k(a, b, c, 0, 0, 0);
#else
    asm("v_mfma_f32_16x16x16_bf16 %0, %1, %2, %0" : "+v"(c) : "v"(a), "v"(b));
    return c;
#endif
#else
    (void)a; (void)b;
    return c;
#endif
}

// --------------------------------- fused converts: x f32->bf16, weights f32->bf16^T
// grid (32, 32, 12): z<4 -> weight transpose tile; z>=4 -> x chunk. (R18, verified)
__global__ void convert_all(const float* __restrict__ x,
                            const float* __restrict__ w0, const float* __restrict__ w1,
                            const float* __restrict__ w2, const float* __restrict__ w3,
                            unsigned short* __restrict__ xb,
                            unsigned short* __restrict__ t0, unsigned short* __restrict__ t1,
                            unsigned short* __restrict__ t2, unsigned short* __restrict__ t3) {
    int z = blockIdx.z;
    if (z >= 4) {
        int lin = (z - 4) * 1024 + blockIdx.y * 32 + blockIdx.x;   // 0..8191
        int i = (lin * 256 + threadIdx.x) * 4;
        float4 v = *(const float4*)(x + i);
        ushort4 o;
        o.x = f2bf(v.x); o.y = f2bf(v.y); o.z = f2bf(v.z); o.w = f2bf(v.w);
        *(ushort4*)(xb + i) = o;
        return;
    }
    __shared__ float tile[64][65];
    const float* src = (z == 0) ? w0 : (z == 1) ? w1 : (z == 2) ? w2 : w3;
    unsigned short* dst = (z == 0) ? t0 : (z == 1) ? t1 : (z == 2) ? t2 : t3;
    int r0 = blockIdx.y * 64, c0 = blockIdx.x * 64;
    int t = threadIdx.x;
    for (int i = t; i < 64 * 64; i += 256) {
        int r = i >> 6, c = i & 63;
        tile[r][c] = src[(size_t)(r0 + r) * HID + c0 + c];
    }
    __syncthreads();
    for (int i = t; i < 64 * 64; i += 256) {
        int r = i & 63, c = i >> 6;
        dst[(size_t)(c0 + c) * HID + r0 + r] = f2bf(tile[r][c]);
    }
}

// ---- counted waits (asm literals need compile-time dispatch) -----------------
__device__ __forceinline__ void sched0() { __builtin_amdgcn_sched_barrier(0); }
__device__ __forceinline__ void w_lgkm4() { asm volatile("s_waitcnt lgkmcnt(4)" ::: "memory"); sched0(); }
__device__ __forceinline__ void w_lgkm0() { asm volatile("s_waitcnt lgkmcnt(0)" ::: "memory"); sched0(); }
template <int NJ> __device__ __forceinline__ void w_lgkm_4nj() {
    if constexpr (NJ == 3) { asm volatile("s_waitcnt lgkmcnt(7)" ::: "memory"); }
    else                   { asm volatile("s_waitcnt lgkmcnt(6)" ::: "memory"); }
    sched0();
}
template <int NJ> __device__ __forceinline__ void w_vm_ns() {
    if constexpr (NJ == 3) { asm volatile("s_waitcnt vmcnt(7)" ::: "memory"); }
    else                   { asm volatile("s_waitcnt vmcnt(6)" ::: "memory"); }
    sched0();
}
__device__ __forceinline__ void w_vm4() { asm volatile("s_waitcnt vmcnt(4)" ::: "memory"); sched0(); }
__device__ __forceinline__ void w_vm0() { asm volatile("s_waitcnt vmcnt(0)" ::: "memory"); sched0(); }
__device__ __forceinline__ void barx() {
    asm volatile("" ::: "memory");
    __builtin_amdgcn_s_barrier();
    asm volatile("" ::: "memory");
}

// ---------------------------------------------------------------- GEMM 256xBN (R14, frozen)
// C[4096][N] = A @ Bt^T + bias; A,Bt bf16, fp32 acc. BN = NJ*64.
// MODE 1: fused QKV, N=6144, Bt0 = contiguous [6144][2048]. NJ=3 -> grid 512 (2 rounds).
// MODE 0: out-proj, N=2048, f32 out. NJ=2 -> grid 256 (1 round).
template <int MODE, int NJ>
__launch_bounds__(512, 2)
__global__ void gemmT(const unsigned short* __restrict__ A,
                      const unsigned short* __restrict__ Bt0,
                      const float* __restrict__ bias0,
                      const float* __restrict__ bias1,
                      const float* __restrict__ bias2,
                      unsigned short* __restrict__ C0,
                      unsigned short* __restrict__ C1,
                      unsigned short* __restrict__ C2,
                      float* __restrict__ Cf) {
    constexpr int BN = NJ * 64;
    __shared__ __align__(16) unsigned short lds[2 * 16384 + 2 * NJ * 4096];
    unsigned short* const A0 = lds;
    unsigned short* const A1 = lds + 16384;
    unsigned short* const B0 = lds + 32768;
    unsigned short* const B1 = lds + 32768 + NJ * 4096;

    const int CPX = (MODE == 1) ? 64 : 32;      // blocks per XCD (bijective: nwg%8==0)
    int vb = (blockIdx.x & 7) * CPX + (blockIdx.x >> 3);
    int m0  = (vb & 15) * 256;
    int n0g = (vb >> 4) * BN;                   // fused col (0..6143 / 0..2047)

    int tid = threadIdx.x;
    int lane = tid & 63;
    int wv_ = tid >> 6;
    int wr = wv_ >> 2, wc = wv_ & 3;            // 2x4 wave grid; wave tile 128 x (NJ*16)
    int l15 = lane & 15, quad = lane >> 4;

    int tr = tid >> 3;
    int tc = ((tid & 7) ^ (tr & 7)) << 3;
    const unsigned short* gA = A   + (size_t)(m0  + tr) * HID + tc;
    const unsigned short* gB = Bt0 + (size_t)(n0g + tr) * HID + tc;
    const int td8 = tid * 8;

    int arow0 = (wr * 128 + l15) * 64;          // + mi*1024
    int brow0 = (wc * (16 * NJ) + l15) * 64;    // + nj*1024
    int sw0 = ((quad ^ (l15 & 7)) << 3);        // kk=0
    int sw1 = (((4 + quad) ^ (l15 & 7)) << 3);  // kk=1

    f32x4 acc[8][NJ];
#pragma unroll
    for (int i = 0; i < 8; ++i)
#pragma unroll
        for (int j = 0; j < NJ; ++j) acc[i][j] = (f32x4){0.f, 0.f, 0.f, 0.f};

    bf16x8 aX[4], aY[4], b0v[NJ], b1v[NJ];

#define STAGE(kt, AD, BD) do { int _kc = (kt) * 64;                          \
    gl2lds16(gA + _kc,             (AD) + td8);                              \
    gl2lds16(gA + 64 * HID + _kc,  (AD) + 4096 + td8);                       \
    gl2lds16(gA + 128 * HID + _kc, (AD) + 8192 + td8);                       \
    gl2lds16(gA + 192 * HID + _kc, (AD) + 12288 + td8);                      \
    _Pragma("unroll")                                                        \
    for (int _r = 0; _r < NJ; ++_r)                                          \
        gl2lds16(gB + (size_t)(_r * 64) * HID + _kc, (BD) + _r * 4096 + td8); } while (0)

#define LDA4(dst, AD, QB, SW) do {                                           \
    dst[0] = *(const bf16x8*)((AD) + arow0 + ((QB) + 0) * 1024 + (SW));      \
    dst[1] = *(const bf16x8*)((AD) + arow0 + ((QB) + 1) * 1024 + (SW));      \
    dst[2] = *(const bf16x8*)((AD) + arow0 + ((QB) + 2) * 1024 + (SW));      \
    dst[3] = *(const bf16x8*)((AD) + arow0 + ((QB) + 3) * 1024 + (SW)); } while (0)

#define LDB(dst, BD, SW) do {                                                \
    _Pragma("unroll")                                                        \
    for (int _n = 0; _n < NJ; ++_n)                                          \
        dst[_n] = *(const bf16x8*)((BD) + brow0 + _n * 1024 + (SW)); } while (0)

#define MF(Q, a, b) do {                                                     \
    __builtin_amdgcn_s_setprio(1);                                           \
    _Pragma("unroll")                                                        \
    for (int mi = 0; mi < 4; ++mi)                                           \
        _Pragma("unroll")                                                    \
        for (int nj = 0; nj < NJ; ++nj)                                      \
            acc[(Q) * 4 + mi][nj] =                                          \
                __builtin_amdgcn_mfma_f32_16x16x32_bf16(a[mi], b[nj],        \
                                                        acc[(Q) * 4 + mi][nj], 0, 0, 0); \
    __builtin_amdgcn_s_setprio(0); } while (0)

#define TILE(AD, BD, AN, BN_, ks) do {                                       \
    LDA4(aY, AD, 4, sw0);            /* ds: 8+NJ */                          \
    w_lgkm4();                       /* aX,b0v ready; aY rides */            \
    MF(0, aX, b0v);                                                          \
    LDA4(aX, AD, 0, sw1);                                                    \
    LDB(b1v, BD, sw1);               /* ds: aY4 + 4+NJ */                    \
    w_lgkm_4nj<NJ>();                /* aY ready */                          \
    MF(1, aY, b0v);                                                          \
    LDA4(aY, AD, 4, sw1);            /* ds: 8+NJ */                          \
    w_lgkm4();                       /* aX,b1v ready */                      \
    MF(0, aX, b1v);                                                          \
    w_lgkm0();                       /* all my (AD,BD) reads done */         \
    barx();                          /* all waves done reading (AD,BD) */    \
    STAGE(ks, AD, BD);               /* vm: old 4+NJ + new 4+NJ */           \
    w_vm_ns<NJ>();                   /* stage(t+1 -> AN,BN_) complete */     \
    barx();                          /* (AN,BN_) certified for all */        \
    LDA4(aX, AN, 0, sw0);                                                    \
    LDB(b0v, BN_, sw0);              /* next-tile kk0 reads in flight */     \
    sched0();                                                                \
    MF(1, aY, b1v);                  /* rides over next-tile reads */        \
} while (0)

    STAGE(0, A0, B0);
    STAGE(1, A1, B1);
    w_vm_ns<NJ>();
    barx();
    LDA4(aX, A0, 0, sw0);
    LDB(b0v, B0, sw0);

    for (int t = 0; t < 32; t += 2) {
        TILE(A0, B0, A1, B1, (t + 2 < 32) ? t + 2 : 31);
        TILE(A1, B1, A0, B0, (t + 3 < 32) ? t + 3 : 31);
    }
    asm volatile("s_waitcnt vmcnt(0) lgkmcnt(0)" ::: "memory");

#undef TILE
#undef STAGE
#undef LDA4
#undef LDB
#undef MF

    // ---- epilogue (pack formulas verbatim; z selected per column for fused tiles)
#pragma unroll
    for (int j = 0; j < NJ; ++j) {
        int n = n0g + wc * (16 * NJ) + j * 16 + l15;    // fused col
        int zj = (MODE == 1) ? (n >> 11) : 0;
        int nn = (MODE == 1) ? (n & 2047) : n;
        float bn = (MODE == 1)
                     ? ((zj == 0) ? bias0[nn] : (zj == 1) ? bias1[nn] : bias2[nn])
                     : bias0[nn];
        unsigned short* Cz = (zj == 0) ? C0 : (zj == 1) ? C1 : C2;
#pragma unroll
        for (int i = 0; i < 8; ++i) {
            int mb = m0 + wr * 128 + i * 16 + quad * 4;   // base row, regs = mb..mb+3
            if (MODE == 1 && zj == 2) {
                // V-pack: 4 regs = 4 consecutive keys (e=0..3) -> one ushort4.
                int b = mb >> 11, s = mb & 2047, h = nn >> 7, d = nn & 127;
                int kt = s >> 4, qv = (s >> 2) & 3, ct = d >> 4, lv = d & 15;
                size_t addr = ((((size_t)((b << 4) + h) * 128 + kt) * 4 + (ct >> 1)) * 4 + qv) * 128
                              + lv * 8 + (ct & 1) * 4;
                ushort4 o;
                o.x = f2bf(acc[i][j][0] + bn);
                o.y = f2bf(acc[i][j][1] + bn);
                o.z = f2bf(acc[i][j][2] + bn);
                o.w = f2bf(acc[i][j][3] + bn);
                *(ushort4*)&Cz[addr] = o;
            } else {
#pragma unroll
                for (int reg = 0; reg < 4; ++reg) {
                    int m = mb + reg;
                    float v = acc[i][j][reg] + bn;
                    if (MODE == 0) {
                        Cf[(size_t)m * HID + nn] = v;
                    } else {
                        int b = m >> 11, s = m & 2047, h = nn >> 7, d = nn & 127;
                        if (zj == 1) {
                            // K-pack: key=s -> (kt, lk); d -> (kk, qk, e)
                            int kt = s >> 4, lk = s & 15, kk = d >> 5, qk = (d >> 3) & 3, e = d & 7;
                            size_t addr = ((((size_t)((b << 4) + h) * 128 + kt) * 4 + kk) * 4 + qk) * 128
                                          + lk * 8 + e;
                            Cz[addr] = f2bf(v);
                        } else {
                            Cz[(size_t)(((b << 4) + h) * S_LEN + s) * HDIM + d] = f2bf(v);
                        }
                    }
                }
            }
        }
    }
}

// ---------------------------------------------------------------- flash attention (R19)
// Block = 4 waves = one 64-row q-block; wave w owns strip s=4q+w fully.
// 2 tiles per sync step (16KB chunk), dbuf 32KB LDS; 4 blocks/CU; heavy-first q.
__launch_bounds__(256, 4)
__global__ void attn_kernel(const unsigned short* __restrict__ Qg,
                            const unsigned short* __restrict__ Kp,
                            const unsigned short* __restrict__ Vp,
                            unsigned short* __restrict__ O) {
    __shared__ __align__(16) unsigned short kv[2][8192];  // [chunk][t0K t0V t1K t1V]

    int linear = blockIdx.x;                  // 0..1023
    int xcd = linear & 7;
    int u = linear >> 3;                      // 0..127
    int bh = xcd * 4 + (u >> 5);              // 4 bh per XCD (K/V 4MB ~ L2)
    int q = 31 - (u & 31);                    // heavy q-blocks launch first
    int b = bh >> 4, h = bh & 15;

    int tid = threadIdx.x, lane = tid & 63, w = tid >> 6;
    int l15 = lane & 15, quad = lane >> 4;

    int s  = 4 * q + w;                       // my strip (diagonal tile = s)
    int r0 = s * 16;
    int NC = 2 * q + 2;                       // 2-tile chunks (N = 4q+4 tiles, even)

    const unsigned short* Qb = Qg + (size_t)bh * (S_LEN * HDIM);
    const unsigned short* Kg = Kp + (size_t)bh * 262144;
    const unsigned short* Vg = Vp + (size_t)bh * 262144;
    const float k2 = 0.08838834764831845f * 1.4426950408889634f;  // scale*log2(e)

    const int frag = quad * 128 + l15 * 8;    // in-tile fragment offset (elems)
    const int td8 = tid * 8;                  // staging offset: tid*16B

#define VLO(x) __builtin_shufflevector(x, x, 0, 1, 2, 3)
#define VHI(x) __builtin_shufflevector(x, x, 4, 5, 6, 7)
    // stage chunk c (tiles 2c, 2c+1) into buffer bf: 4 ops of 4KB
#define ASTAGE2(c, bf) do {                                                    \
    size_t _g0 = (size_t)(2 * (c)) * 2048 + td8;                               \
    size_t _g1 = (size_t)(2 * (c) + 1) * 2048 + td8;                           \
    gl2lds16(Kg + _g0, &kv[bf][td8]);                                          \
    gl2lds16(Vg + _g0, &kv[bf][2048 + td8]);                                   \
    gl2lds16(Kg + _g1, &kv[bf][4096 + td8]);                                   \
    gl2lds16(Vg + _g1, &kv[bf][6144 + td8]); } while (0)

    bf16x8 qf[4];
#pragma unroll
    for (int kk = 0; kk < 4; ++kk)
        qf[kk] = *(const bf16x8*)&Qb[(size_t)(r0 + l15) * HDIM + kk * 32 + quad * 8];

    f32x4 o_acc[8];
#pragma unroll
    for (int c = 0; c < 8; ++c) o_acc[c] = (f32x4){0.f, 0.f, 0.f, 0.f};
    float l_part = 0.f;

    // one tile from LDS half: verbatim R17 math; mask doff = kt - s (wave-uniform)
#define COMP(kt, bf, half) do {                                                \
    const unsigned short* KL = &kv[bf][(half) * 4096 + frag];                  \
    const unsigned short* VL = KL + 2048;                                      \
    bf16x8 kb0 = *(const bf16x8*)(KL);                                         \
    bf16x8 kb1 = *(const bf16x8*)(KL + 512);                                   \
    bf16x8 kb2 = *(const bf16x8*)(KL + 1024);                                  \
    bf16x8 kb3 = *(const bf16x8*)(KL + 1536);                                  \
    bf16x8 v0 = *(const bf16x8*)(VL);                                          \
    bf16x8 v1 = *(const bf16x8*)(VL + 512);                                    \
    bf16x8 v2 = *(const bf16x8*)(VL + 1024);                                   \
    bf16x8 v3 = *(const bf16x8*)(VL + 1536);                                   \
    f32x4 st0 = (f32x4){0.f, 0.f, 0.f, 0.f};                                   \
    f32x4 st1 = (f32x4){0.f, 0.f, 0.f, 0.f};                                   \
    __builtin_amdgcn_s_setprio(1);                                             \
    st0 = __builtin_amdgcn_mfma_f32_16x16x32_bf16(kb0, qf[0], st0, 0, 0, 0);   \
    st1 = __builtin_amdgcn_mfma_f32_16x16x32_bf16(kb1, qf[1], st1, 0, 0, 0);   \
    st0 = __builtin_amdgcn_mfma_f32_16x16x32_bf16(kb2, qf[2], st0, 0, 0, 0);   \
    st1 = __builtin_amdgcn_mfma_f32_16x16x32_bf16(kb3, qf[3], st1, 0, 0, 0);   \
    __builtin_amdgcn_s_setprio(0);                                             \
    f32x4 stv = st0 + st1;                                                     \
    float p0, p1, p2, p3;                                                      \
    int doff = (kt) - s;                                                       \
    if (doff >= 0) {                                                           \
        int d16 = doff << 4;                                                   \
        p0 = (d16 + quad * 4 + 0 <= l15) ? exp2f(stv[0] * k2) : 0.f;           \
        p1 = (d16 + quad * 4 + 1 <= l15) ? exp2f(stv[1] * k2) : 0.f;           \
        p2 = (d16 + quad * 4 + 2 <= l15) ? exp2f(stv[2] * k2) : 0.f;           \
        p3 = (d16 + quad * 4 + 3 <= l15) ? exp2f(stv[3] * k2) : 0.f;           \
    } else {                                                                   \
        p0 = exp2f(stv[0] * k2); p1 = exp2f(stv[1] * k2);                      \
        p2 = exp2f(stv[2] * k2); p3 = exp2f(stv[3] * k2);                      \
    }                                                                          \
    l_part += (p0 + p1) + (p2 + p3);                                           \
    bf16x4 pf;                                                                 \
    pf[0] = (short)f2bf(p0); pf[1] = (short)f2bf(p1);                          \
    pf[2] = (short)f2bf(p2); pf[3] = (short)f2bf(p3);                          \
    __builtin_amdgcn_s_setprio(1);                                             \
    o_acc[0] = pv_mfma(pf, VLO(v0), o_acc[0]);                                 \
    o_acc[1] = pv_mfma(pf, VHI(v0), o_acc[1]);                                 \
    o_acc[2] = pv_mfma(pf, VLO(v1), o_acc[2]);                                 \
    o_acc[3] = pv_mfma(pf, VHI(v1), o_acc[3]);                                 \
    o_acc[4] = pv_mfma(pf, VLO(v2), o_acc[4]);                                 \
    o_acc[5] = pv_mfma(pf, VHI(v2), o_acc[5]);                                 \
    o_acc[6] = pv_mfma(pf, VLO(v3), o_acc[6]);                                 \
    o_acc[7] = pv_mfma(pf, VHI(v3), o_acc[7]);                                 \
    __builtin_amdgcn_s_setprio(0);                                             \
} while (0)

    ASTAGE2(0, 0);
    for (int c = 0; c < NC; ++c) {
        int nc2 = (c + 1 < NC) ? c + 1 : c;       // uniform dummy re-stage at end
        ASTAGE2(nc2, (c + 1) & 1);
        w_vm4();                                  // chunk c landed (4 newest = c+1)
        barx();                                   // all waves: chunk c staged
        COMP(2 * c,     (c & 1), 0);
        COMP(2 * c + 1, (c & 1), 1);
        barx();                                   // reads of buf[c&1] done
    }
    w_vm0();                                      // drain dummy stage

    // ---- epilogue: normalizer over quads, write O rows r0..r0+15
    float lp = l_part;
    lp += __shfl_xor(lp, 16, 64);
    lp += __shfl_xor(lp, 32, 64);
#pragma unroll
    for (int reg = 0; reg < 4; ++reg) {
        float l = __shfl(lp, quad * 4 + reg, 64);
        float inv = 1.f / l;
        int srow = r0 + quad * 4 + reg;
        unsigned short* op = O + (size_t)(b * S_LEN + srow) * HID + h * HDIM;
#pragma unroll
        for (int ct = 0; ct < 8; ++ct)
            op[ct * 16 + l15] = f2bf(o_acc[ct][reg] * inv);
    }

#undef COMP
#undef ASTAGE2
#undef VLO
#undef VHI
}

// ---------------------------------------------------------------- launch
extern "C" void kernel_launch(void* const* d_in, const int* in_sizes, int n_in,
                              void* d_out, int out_size, void* d_ws, size_t ws_size,
                              hipStream_t stream) {
    (void)in_sizes; (void)n_in; (void)out_size; (void)ws_size;
    const float* x  = (const float*)d_in[0];
    const float* wq = (const float*)d_in[2];
    const float* bq = (const float*)d_in[3];
    const float* wk = (const float*)d_in[4];
    const float* bk = (const float*)d_in[5];
    const float* wv = (const float*)d_in[6];
    const float* bv = (const float*)d_in[7];
    const float* wo = (const float*)d_in[8];
    const float* bo = (const float*)d_in[9];
    float* out = (float*)d_out;

    unsigned short* ws = (unsigned short*)d_ws;
    const size_t WSZ = 4194304;
    unsigned short* wqT = ws;                // [0, 4M)   wqT/wkT/wvT contiguous =
    unsigned short* wkT = ws + WSZ;          // [4M, 8M)  fused [6144][2048] B for QKV
    unsigned short* wvT = ws + 2 * WSZ;      // [8M, 12M)
    unsigned short* woT = ws + 3 * WSZ;      // [12M, 16M)
    unsigned short* xb  = ws + 4 * WSZ;      // [16M, 24M)
    unsigned short* Ab  = ws + 4 * WSZ;      // aliases xb (dead after QKV gemm)
    unsigned short* Qb  = ws + 6 * WSZ;      // [24M, 32M)
    unsigned short* Kb  = ws + 8 * WSZ;      // [32M, 40M)  fragment-packed
    unsigned short* Vb  = ws + 10 * WSZ;     // [40M, 48M)  fragment-packed

    convert_all<<<dim3(32, 32, 12), 256, 0, stream>>>(x, wq, wk, wv, wo,
                                                      xb, wqT, wkT, wvT, woT);
    gemmT<1, 3><<<dim3(512), 512, 0, stream>>>(xb, wqT, bq, bk, bv,
                                               Qb, Kb, Vb, nullptr);
    attn_kernel<<<dim3(1024), 256, 0, stream>>>(Qb, Kb, Vb, Ab);
    gemmT<0, 2><<<dim3(256), 512, 0, stream>>>(Ab, woT, bo, nullptr, nullptr,
                                               nullptr, nullptr, nullptr, out);
}

// Round 13
// 393.934 us; speedup vs baseline: 1.0425x; 1.0425x over previous
//
#include <hip/hip_runtime.h>

// CausalSelfAttention: B=2, S=2048, H=2048, NH=16, HD=128. f32 in/out, bf16 MFMA inside.
// R20 = faithful m201 8-phase port for QKV GEMM + R17 attn (best measured) +
// R14 outproj + R18 fused converts.
// R15's "8-phase" failed because it DRAINED vmcnt(0) per tile and staged in one
// burst; m218: counted-vs-drain0 inside 8-phase = +38-73%. R20 follows the
// template exactly: per phase {quadrant ds-reads | stage ONE half-tile (2 ops) |
// bar | lgkm0 | setprio+16 MFMA | bar}; vmcnt(4) ONLY at phases 4/8 (never 0);
// stage->certify distance 3-6 phases. Ledger verified by op-count simulation:
// prologue {A0lo,A0hi,B0lo,B0hi(t0), A1lo,B1lo(t1)}+vm4; ph1:A1hi(t+1),
// ph2:B1hi(t+1), ph3:A0lo(t+2), ph4:B0lo(t+2)+vm4, ph5:A0hi(t+2), ph6:B0hi(t+2),
// ph7:A1lo(t+3), ph8:B1lo(t+3)+vm4. Tile 256x256, grid 384 (1.5 rounds, -25%
// accepted: m201-class 1563 TF x 0.75 ~ 88us < 118us at R14 floor).
// Swizzle + epilogue pack verbatim from refchecked R13/R14.

using bf16x8 = __attribute__((ext_vector_type(8))) short;
using bf16x4 = __attribute__((ext_vector_type(4))) short;
using f32x4  = __attribute__((ext_vector_type(4))) float;

#define S_LEN 2048
#define NHEAD 16
#define HDIM  128
#define HID   2048

__device__ __forceinline__ unsigned short f2bf(float f) {
    unsigned int u = __float_as_uint(f);
    u += 0x7fffu + ((u >> 16) & 1u);   // round-to-nearest-even
    return (unsigned short)(u >> 16);
}
__device__ __forceinline__ void gl2lds16(const void* g, void* l) {
    __builtin_amdgcn_global_load_lds(
        (const __attribute__((address_space(1))) void*)g,
        (__attribute__((address_space(3))) void*)l, 16, 0, 0);
}

// 16x16x16 bf16 MFMA, device-guarded (host pass must not reference the builtin).
__device__ __forceinline__ f32x4 pv_mfma(bf16x4 a, bf16x4 b, f32x4 c) {
#if defined(__HIP_DEVICE_COMPILE__)
#if __has_builtin(__builtin_amdgcn_mfma_f32_16x16x16bf16_1k)
    return __builtin_amdgcn_mfma_f32_16x16x16bf16_1k(a, b, c, 0, 0, 0);
#else
    asm("v_mfma_f32_16x16x16_bf16 %0, %1, %2, %0" : "+v"(c) : "v"(a), "v"(b));
    return c;
#endif
#else
    (void)a; (void)b;
    return c;
#endif
}

// --------------------------------- fused converts: x f32->bf16, weights f32->bf16^T
__global__ void convert_all(const float* __restrict__ x,
                            const float* __restrict__ w0, const float* __restrict__ w1,
                            const float* __restrict__ w2, const float* __restrict__ w3,
                            unsigned short* __restrict__ xb,
                            unsigned short* __restrict__ t0, unsigned short* __restrict__ t1,
                            unsigned short* __restrict__ t2, unsigned short* __restrict__ t3) {
    int z = blockIdx.z;
    if (z >= 4) {
        int lin = (z - 4) * 1024 + blockIdx.y * 32 + blockIdx.x;   // 0..8191
        int i = (lin * 256 + threadIdx.x) * 4;
        float4 v = *(const float4*)(x + i);
        ushort4 o;
        o.x = f2bf(v.x); o.y = f2bf(v.y); o.z = f2bf(v.z); o.w = f2bf(v.w);
        *(ushort4*)(xb + i) = o;
        return;
    }
    __shared__ float tile[64][65];
    const float* src = (z == 0) ? w0 : (z == 1) ? w1 : (z == 2) ? w2 : w3;
    unsigned short* dst = (z == 0) ? t0 : (z == 1) ? t1 : (z == 2) ? t2 : t3;
    int r0 = blockIdx.y * 64, c0 = blockIdx.x * 64;
    int t = threadIdx.x;
    for (int i = t; i < 64 * 64; i += 256) {
        int r = i >> 6, c = i & 63;
        tile[r][c] = src[(size_t)(r0 + r) * HID + c0 + c];
    }
    __syncthreads();
    for (int i = t; i < 64 * 64; i += 256) {
        int r = i & 63, c = i >> 6;
        dst[(size_t)(c0 + c) * HID + r0 + r] = f2bf(tile[r][c]);
    }
}

// ---- sync helpers -----------------------------------------------------------
__device__ __forceinline__ void sched0() { __builtin_amdgcn_sched_barrier(0); }
__device__ __forceinline__ void w_lgkm8() { asm volatile("s_waitcnt lgkmcnt(8)" ::: "memory"); sched0(); }
__device__ __forceinline__ void w_lgkm4() { asm volatile("s_waitcnt lgkmcnt(4)" ::: "memory"); sched0(); }
__device__ __forceinline__ void w_lgkm0() { asm volatile("s_waitcnt lgkmcnt(0)" ::: "memory"); sched0(); }
__device__ __forceinline__ void w_vm6() { asm volatile("s_waitcnt vmcnt(6)" ::: "memory"); sched0(); }
__device__ __forceinline__ void w_vm4() { asm volatile("s_waitcnt vmcnt(4)" ::: "memory"); sched0(); }
__device__ __forceinline__ void w_vm2() { asm volatile("s_waitcnt vmcnt(2)" ::: "memory"); sched0(); }
__device__ __forceinline__ void w_vm0() { asm volatile("s_waitcnt vmcnt(0)" ::: "memory"); sched0(); }
__device__ __forceinline__ void barx() {
    asm volatile("" ::: "memory");
    __builtin_amdgcn_s_barrier();
    asm volatile("" ::: "memory");
}

// ---------------------------------------------------------------- QKV GEMM 8-phase (R20)
// C[4096][6144] = A @ Bt^T + bias (fused QKV, Bt = contiguous [6144][2048]).
// 256x256 tile, BK=64, 8 waves 2x4 (wave tile 128x64), LDS 128KB (2buf x 2half).
__launch_bounds__(512, 2)
__global__ void gemm8p(const unsigned short* __restrict__ A,
                       const unsigned short* __restrict__ Bt,
                       const float* __restrict__ bias0,
                       const float* __restrict__ bias1,
                       const float* __restrict__ bias2,
                       unsigned short* __restrict__ C0,
                       unsigned short* __restrict__ C1,
                       unsigned short* __restrict__ C2) {
    __shared__ __align__(16) unsigned short lds[65536];   // 128KB
    unsigned short* const A0 = lds;            // A buf0: half0 [0,8192), half1 [8192,16384)
    unsigned short* const A1 = lds + 16384;
    unsigned short* const B0 = lds + 32768;
    unsigned short* const B1 = lds + 49152;

    int vb = (blockIdx.x & 7) * 48 + (blockIdx.x >> 3);   // 384 blocks, bijective
    int m0  = (vb & 15) * 256;
    int n0g = (vb >> 4) * 256;
    int z   = n0g >> 11;
    int nb0 = n0g & 2047;

    int tid = threadIdx.x;
    int lane = tid & 63;
    int wv_ = tid >> 6;
    int wr = wv_ >> 2, wc = wv_ & 3;            // 2x4 wave grid; wave tile 128x64
    int l15 = lane & 15, quad = lane >> 4;

    // staging: 512 thr x 16B = 64 rows/issue; half-tile (128 rows) = 2 issues.
    // T2 pre-swizzled source (verified): LDS 16B-slot s of row r holds col-slot s^(r&7).
    int tr = tid >> 3;
    int tc = ((tid & 7) ^ (tr & 7)) << 3;
    const unsigned short* gA = A  + (size_t)(m0  + tr) * HID + tc;
    const unsigned short* gB = Bt + (size_t)(n0g + tr) * HID + tc;
    const int td8 = tid * 8;

    int arow0 = (wr * 128 + l15) * 64;          // + hm*4096 + mi*1024
    int brow0 = (wc * 64 + l15) * 64;           // + hn*2048 + nj*1024
    int swz[2] = { ((quad ^ (l15 & 7)) << 3), (((4 + quad) ^ (l15 & 7)) << 3) };

    f32x4 acc[8][4];
#pragma unroll
    for (int i = 0; i < 8; ++i)
#pragma unroll
        for (int j = 0; j < 4; ++j) acc[i][j] = (f32x4){0.f, 0.f, 0.f, 0.f};

    bf16x8 av[2][4];      // [kk][mi] for current mi-half
    bf16x8 bv[2][2][2];   // [hn][kk][nj], persistent per tile

#define SGA(kt, half, AD) do {                                               \
    size_t _g = (size_t)((half) * 128) * HID + (size_t)(kt) * 64;            \
    gl2lds16(gA + _g,            (AD) + (half) * 8192 + td8);                \
    gl2lds16(gA + _g + 64 * HID, (AD) + (half) * 8192 + 4096 + td8); } while (0)

#define SGB(kt, half, BD) do {                                               \
    size_t _g = (size_t)((half) * 128) * HID + (size_t)(kt) * 64;            \
    gl2lds16(gB + _g,            (BD) + (half) * 8192 + td8);                \
    gl2lds16(gB + _g + 64 * HID, (BD) + (half) * 8192 + 4096 + td8); } while (0)

#define RDAV(AD, hm) do {                                                    \
    _Pragma("unroll")                                                        \
    for (int kk = 0; kk < 2; ++kk)                                           \
        _Pragma("unroll")                                                    \
        for (int mi = 0; mi < 4; ++mi)                                       \
            av[kk][mi] = *(const bf16x8*)((AD) + arow0 + (hm) * 4096         \
                                          + mi * 1024 + swz[kk]); } while (0)

#define RDBV(BD, hn) do {                                                    \
    _Pragma("unroll")                                                        \
    for (int kk = 0; kk < 2; ++kk)                                           \
        _Pragma("unroll")                                                    \
        for (int nj = 0; nj < 2; ++nj)                                       \
            bv[hn][kk][nj] = *(const bf16x8*)((BD) + brow0 + (hn) * 2048     \
                                              + nj * 1024 + swz[kk]); } while (0)

#define MFQ(hm, hn) do {                                                     \
    __builtin_amdgcn_s_setprio(1);                                           \
    _Pragma("unroll")                                                        \
    for (int kk = 0; kk < 2; ++kk)                                           \
        _Pragma("unroll")                                                    \
        for (int mi = 0; mi < 4; ++mi)                                       \
            _Pragma("unroll")                                                \
            for (int nj = 0; nj < 2; ++nj)                                   \
                acc[(hm) * 4 + mi][(hn) * 2 + nj] =                          \
                    __builtin_amdgcn_mfma_f32_16x16x32_bf16(av[kk][mi],      \
                        bv[hn][kk][nj], acc[(hm) * 4 + mi][(hn) * 2 + nj],   \
                        0, 0, 0);                                            \
    __builtin_amdgcn_s_setprio(0); sched0(); } while (0)

    // ---- prologue: tile0 full + tile1 lo halves; certify tile0 (vm4 leaves 2 in flight)
    SGA(0, 0, A0); SGA(0, 1, A0);
    SGB(0, 0, B0); SGB(0, 1, B0);
    SGA(1, 0, A1); SGB(1, 0, B1);
    w_vm4();
    barx();

    for (int it = 0; it < 16; ++it) {
        int t  = 2 * it;
        int t2 = (t + 2 < 32) ? t + 2 : 31;   // dummy re-stage at tail (never read)
        int t3 = (t + 3 < 32) ? t + 3 : 31;
        // ---- ph1: quad(lo,lo) of tile t; stage A1hi(t+1)
        RDAV(A0, 0); RDBV(B0, 0);             // 12 ds_reads
        SGA(t + 1, 1, A1);
        w_lgkm8();
        barx(); w_lgkm0();
        MFQ(0, 0);
        barx();
        // ---- ph2: quad(lo,hi); stage B1hi(t+1)
        RDBV(B0, 1);                           // 4
        SGB(t + 1, 1, B1);
        barx(); w_lgkm0();
        MFQ(0, 1);
        barx();
        // ---- ph3: quad(hi,lo); stage A0lo(t+2)  [A0lo last read ph1]
        RDAV(A0, 1);                           // 8
        SGA(t2, 0, A0);
        barx(); w_lgkm0();
        MFQ(1, 0);
        barx();
        // ---- ph4: quad(hi,hi); stage B0lo(t+2); vmcnt(4) certifies tile t+1 complete
        SGB(t2, 0, B0);
        barx();
        MFQ(1, 1);
        w_vm4();
        barx();
        // ---- ph5: tile t+1, quad(lo,lo); stage A0hi(t+2)
        RDAV(A1, 0); RDBV(B1, 0);
        SGA(t2, 1, A0);
        w_lgkm8();
        barx(); w_lgkm0();
        MFQ(0, 0);
        barx();
        // ---- ph6: quad(lo,hi); stage B0hi(t+2)
        RDBV(B1, 1);
        SGB(t2, 1, B0);
        barx(); w_lgkm0();
        MFQ(0, 1);
        barx();
        // ---- ph7: quad(hi,lo); stage A1lo(t+3)
        RDAV(A1, 1);
        SGA(t3, 0, A1);
        barx(); w_lgkm0();
        MFQ(1, 0);
        barx();
        // ---- ph8: quad(hi,hi); stage B1lo(t+3); vmcnt(4) certifies tile t+2 (buf0)
        SGB(t3, 0, B1);
        barx();
        MFQ(1, 1);
        w_vm4();
        barx();
    }
    asm volatile("s_waitcnt vmcnt(0) lgkmcnt(0)" ::: "memory");

#undef SGA
#undef SGB
#undef RDAV
#undef RDBV
#undef MFQ

    // ---- epilogue (pack formulas verbatim from refchecked R13)
#pragma unroll
    for (int j = 0; j < 4; ++j) {
        int n = nb0 + wc * 64 + j * 16 + l15;
        float bn = (z == 0) ? bias0[n] : (z == 1) ? bias1[n] : bias2[n];
        unsigned short* Cz = (z == 0) ? C0 : (z == 1) ? C1 : C2;
#pragma unroll
        for (int i = 0; i < 8; ++i) {
            int mb = m0 + wr * 128 + i * 16 + quad * 4;   // base row, regs = mb..mb+3
            if (z == 2) {
                // V-pack: 4 regs = 4 consecutive keys (e=0..3) -> one ushort4.
                int b = mb >> 11, s = mb & 2047, h = n >> 7, d = n & 127;
                int kt = s >> 4, qv = (s >> 2) & 3, ct = d >> 4, lv = d & 15;
                size_t addr = ((((size_t)((b << 4) + h) * 128 + kt) * 4 + (ct >> 1)) * 4 + qv) * 128
                              + lv * 8 + (ct & 1) * 4;
                ushort4 o;
                o.x = f2bf(acc[i][j][0] + bn);
                o.y = f2bf(acc[i][j][1] + bn);
                o.z = f2bf(acc[i][j][2] + bn);
                o.w = f2bf(acc[i][j][3] + bn);
                *(ushort4*)&Cz[addr] = o;
            } else {
#pragma unroll
                for (int reg = 0; reg < 4; ++reg) {
                    int m = mb + reg;
                    float v = acc[i][j][reg] + bn;
                    int b = m >> 11, s = m & 2047, h = n >> 7, d = n & 127;
                    if (z == 1) {
                        int kt = s >> 4, lk = s & 15, kk = d >> 5, qk = (d >> 3) & 3, e = d & 7;
                        size_t addr = ((((size_t)((b << 4) + h) * 128 + kt) * 4 + kk) * 4 + qk) * 128
                                      + lk * 8 + e;
                        Cz[addr] = f2bf(v);
                    } else {
                        Cz[(size_t)(((b << 4) + h) * S_LEN + s) * HDIM + d] = f2bf(v);
                    }
                }
            }
        }
    }
}

// ---------------------------------------------------------------- out-proj GEMM (R14, frozen)
__launch_bounds__(512, 2)
__global__ void gemmO(const unsigned short* __restrict__ A,
                      const unsigned short* __restrict__ Bt0,
                      const float* __restrict__ bias0,
                      float* __restrict__ Cf) {
    constexpr int NJ = 2;
    __shared__ __align__(16) unsigned short lds[2 * 16384 + 2 * NJ * 4096];
    unsigned short* const A0 = lds;
    unsigned short* const A1 = lds + 16384;
    unsigned short* const B0 = lds + 32768;
    unsigned short* const B1 = lds + 32768 + NJ * 4096;

    int vb = (blockIdx.x & 7) * 32 + (blockIdx.x >> 3);
    int m0  = (vb & 15) * 256;
    int n0g = (vb >> 4) * (NJ * 64);

    int tid = threadIdx.x;
    int lane = tid & 63;
    int wv_ = tid >> 6;
    int wr = wv_ >> 2, wc = wv_ & 3;
    int l15 = lane & 15, quad = lane >> 4;

    int tr = tid >> 3;
    int tc = ((tid & 7) ^ (tr & 7)) << 3;
    const unsigned short* gA = A   + (size_t)(m0  + tr) * HID + tc;
    const unsigned short* gB = Bt0 + (size_t)(n0g + tr) * HID + tc;
    const int td8 = tid * 8;

    int arow0 = (wr * 128 + l15) * 64;
    int brow0 = (wc * (16 * NJ) + l15) * 64;
    int sw0 = ((quad ^ (l15 & 7)) << 3);
    int sw1 = (((4 + quad) ^ (l15 & 7)) << 3);

    f32x4 acc[8][NJ];
#pragma unroll
    for (int i = 0; i < 8; ++i)
#pragma unroll
        for (int j = 0; j < NJ; ++j) acc[i][j] = (f32x4){0.f, 0.f, 0.f, 0.f};

    bf16x8 aX[4], aY[4], b0v[NJ], b1v[NJ];

#define STAGE(kt, AD, BD) do { int _kc = (kt) * 64;                          \
    gl2lds16(gA + _kc,             (AD) + td8);                              \
    gl2lds16(gA + 64 * HID + _kc,  (AD) + 4096 + td8);                       \
    gl2lds16(gA + 128 * HID + _kc, (AD) + 8192 + td8);                       \
    gl2lds16(gA + 192 * HID + _kc, (AD) + 12288 + td8);                      \
    _Pragma("unroll")                                                        \
    for (int _r = 0; _r < NJ; ++_r)                                          \
        gl2lds16(gB + (size_t)(_r * 64) * HID + _kc, (BD) + _r * 4096 + td8); } while (0)

#define LDA4(dst, AD, QB, SW) do {                                           \
    dst[0] = *(const bf16x8*)((AD) + arow0 + ((QB) + 0) * 1024 + (SW));      \
    dst[1] = *(const bf16x8*)((AD) + arow0 + ((QB) + 1) * 1024 + (SW));      \
    dst[2] = *(const bf16x8*)((AD) + arow0 + ((QB) + 2) * 1024 + (SW));      \
    dst[3] = *(const bf16x8*)((AD) + arow0 + ((QB) + 3) * 1024 + (SW)); } while (0)

#define LDB(dst, BD, SW) do {                                                \
    _Pragma("unroll")                                                        \
    for (int _n = 0; _n < NJ; ++_n)                                          \
        dst[_n] = *(const bf16x8*)((BD) + brow0 + _n * 1024 + (SW)); } while (0)

#define MF(Q, a, b) do {                                                     \
    __builtin_amdgcn_s_setprio(1);                                           \
    _Pragma("unroll")                                                        \
    for (int mi = 0; mi < 4; ++mi)                                           \
        _Pragma("unroll")                                                    \
        for (int nj = 0; nj < NJ; ++nj)                                      \
            acc[(Q) * 4 + mi][nj] =                                          \
                __builtin_amdgcn_mfma_f32_16x16x32_bf16(a[mi], b[nj],        \
                                                        acc[(Q) * 4 + mi][nj], 0, 0, 0); \
    __builtin_amdgcn_s_setprio(0); } while (0)

#define TILE(AD, BD, AN, BN_, ks) do {                                       \
    LDA4(aY, AD, 4, sw0);                                                    \
    w_lgkm4();                                                               \
    MF(0, aX, b0v);                                                          \
    LDA4(aX, AD, 0, sw1);                                                    \
    LDB(b1v, BD, sw1);                                                       \
    asm volatile("s_waitcnt lgkmcnt(6)" ::: "memory"); sched0();             \
    MF(1, aY, b0v);                                                          \
    LDA4(aY, AD, 4, sw1);                                                    \
    w_lgkm4();                                                               \
    MF(0, aX, b1v);                                                          \
    w_lgkm0();                                                               \
    barx();                                                                  \
    STAGE(ks, AD, BD);                                                       \
    w_vm6();                                                                 \
    barx();                                                                  \
    LDA4(aX, AN, 0, sw0);                                                    \
    LDB(b0v, BN_, sw0);                                                      \
    sched0();                                                                \
    MF(1, aY, b1v);                                                          \
} while (0)

    STAGE(0, A0, B0);
    STAGE(1, A1, B1);
    w_vm6();
    barx();
    LDA4(aX, A0, 0, sw0);
    LDB(b0v, B0, sw0);

    for (int t = 0; t < 32; t += 2) {
        TILE(A0, B0, A1, B1, (t + 2 < 32) ? t + 2 : 31);
        TILE(A1, B1, A0, B0, (t + 3 < 32) ? t + 3 : 31);
    }
    asm volatile("s_waitcnt vmcnt(0) lgkmcnt(0)" ::: "memory");

#undef TILE
#undef STAGE
#undef LDA4
#undef LDB
#undef MF

#pragma unroll
    for (int j = 0; j < NJ; ++j) {
        int n = n0g + wc * (16 * NJ) + j * 16 + l15;
        float bn = bias0[n];
#pragma unroll
        for (int i = 0; i < 8; ++i) {
            int mb = m0 + wr * 128 + i * 16 + quad * 4;
#pragma unroll
            for (int reg = 0; reg < 4; ++reg) {
                int m = mb + reg;
                Cf[(size_t)m * HID + n] = acc[i][j][reg] + bn;
            }
        }
    }
}

// ---------------------------------------------------------------- flash attention (R17, best)
__launch_bounds__(256, 2)
__global__ void attn_kernel(const unsigned short* __restrict__ Qg,
                            const unsigned short* __restrict__ Kp,
                            const unsigned short* __restrict__ Vp,
                            unsigned short* __restrict__ O) {
    __shared__ __align__(16) unsigned short kv[2][4096];   // [buf][K:0..2048 | V:2048..4096]

    int linear = blockIdx.x;                  // 0..511
    int xcd = linear & 7;
    int u = linear >> 3;                      // 0..63
    int bh = xcd * 4 + (u & 3);               // 4 bh per XCD (K/V 4MB ~ L2)
    int q = u >> 2;                           // 0..15 -> pair (q, 31-q)
    int b = bh >> 4, h = bh & 15;

    int tid = threadIdx.x, lane = tid & 63, w = tid >> 6;
    int l15 = lane & 15, quad = lane >> 4;

    const unsigned short* Qb = Qg + (size_t)bh * (S_LEN * HDIM);
    const unsigned short* Kg = Kp + (size_t)bh * 262144;
    const unsigned short* Vg = Vp + (size_t)bh * 262144;
    const float k2 = 0.08838834764831845f * 1.4426950408889634f;  // scale*log2(e)

    const int frag = quad * 128 + l15 * 8;    // in-tile fragment offset (elems)
    const int td8 = tid * 8;                  // staging offset: tid*16B

#define VLO(x) __builtin_shufflevector(x, x, 0, 1, 2, 3)
#define VHI(x) __builtin_shufflevector(x, x, 4, 5, 6, 7)
#define ASTAGE(kt, bf) do { size_t _g = (size_t)(kt) * 2048 + td8;             \
    gl2lds16(Kg + _g, &kv[bf][td8]);                                           \
    gl2lds16(Vg + _g, &kv[bf][2048 + td8]); } while (0)

    auto run_qblock = [&](int qb) {
        int s  = 4 * qb + w;                  // my strip (diagonal tile = s)
        int r0 = s * 16;
        int N  = 4 * qb + 4;                  // staged tiles (block-uniform)

        bf16x8 qf[4];
#pragma unroll
        for (int kk = 0; kk < 4; ++kk)
            qf[kk] = *(const bf16x8*)&Qb[(size_t)(r0 + l15) * HDIM + kk * 32 + quad * 8];

        f32x4 o_acc[8];
#pragma unroll
        for (int c = 0; c < 8; ++c) o_acc[c] = (f32x4){0.f, 0.f, 0.f, 0.f};
        float l_part = 0.f;

        ASTAGE(0, 0);
        for (int kt = 0; kt < N; ++kt) {
            int nk = (kt + 1 < N) ? kt + 1 : kt;      // uniform dummy re-stage at end
            ASTAGE(nk, (kt + 1) & 1);
            w_vm2();                                  // my 2 ops of stage(kt) done
            barx();                                   // all waves: tile kt staged

            const unsigned short* KL = &kv[kt & 1][frag];
            const unsigned short* VL = &kv[kt & 1][2048 + frag];
            bf16x8 kb0 = *(const bf16x8*)(KL);
            bf16x8 kb1 = *(const bf16x8*)(KL + 512);
            bf16x8 kb2 = *(const bf16x8*)(KL + 1024);
            bf16x8 kb3 = *(const bf16x8*)(KL + 1536);
            bf16x8 v0 = *(const bf16x8*)(VL);
            bf16x8 v1 = *(const bf16x8*)(VL + 512);
            bf16x8 v2 = *(const bf16x8*)(VL + 1024);
            bf16x8 v3 = *(const bf16x8*)(VL + 1536);

            f32x4 st0 = (f32x4){0.f, 0.f, 0.f, 0.f};
            f32x4 st1 = (f32x4){0.f, 0.f, 0.f, 0.f};
            __builtin_amdgcn_s_setprio(1);
            st0 = __builtin_amdgcn_mfma_f32_16x16x32_bf16(kb0, qf[0], st0, 0, 0, 0);
            st1 = __builtin_amdgcn_mfma_f32_16x16x32_bf16(kb1, qf[1], st1, 0, 0, 0);
            st0 = __builtin_amdgcn_mfma_f32_16x16x32_bf16(kb2, qf[2], st0, 0, 0, 0);
            st1 = __builtin_amdgcn_mfma_f32_16x16x32_bf16(kb3, qf[3], st1, 0, 0, 0);
            __builtin_amdgcn_s_setprio(0);
            f32x4 stv = st0 + st1;

            float p0, p1, p2, p3;
            int doff = kt - s;                        // wave-uniform
            if (doff >= 0) {
                int d16 = doff << 4;
                p0 = (d16 + quad * 4 + 0 <= l15) ? exp2f(stv[0] * k2) : 0.f;
                p1 = (d16 + quad * 4 + 1 <= l15) ? exp2f(stv[1] * k2) : 0.f;
                p2 = (d16 + quad * 4 + 2 <= l15) ? exp2f(stv[2] * k2) : 0.f;
                p3 = (d16 + quad * 4 + 3 <= l15) ? exp2f(stv[3] * k2) : 0.f;
            } else {
                p0 = exp2f(stv[0] * k2); p1 = exp2f(stv[1] * k2);
                p2 = exp2f(stv[2] * k2); p3 = exp2f(stv[3] * k2);
            }
            l_part += (p0 + p1) + (p2 + p3);

            bf16x4 pf;
            pf[0] = (short)f2bf(p0); pf[1] = (short)f2bf(p1);
            pf[2] = (short)f2bf(p2); pf[3] = (short)f2bf(p3);

            __builtin_amdgcn_s_setprio(1);
            o_acc[0] = pv_mfma(pf, VLO(v0), o_acc[0]);
            o_acc[1] = pv_mfma(pf, VHI(v0), o_acc[1]);
            o_acc[2] = pv_mfma(pf, VLO(v1), o_acc[2]);
            o_acc[3] = pv_mfma(pf, VHI(v1), o_acc[3]);
            o_acc[4] = pv_mfma(pf, VLO(v2), o_acc[4]);
            o_acc[5] = pv_mfma(pf, VHI(v2), o_acc[5]);
            o_acc[6] = pv_mfma(pf, VLO(v3), o_acc[6]);
            o_acc[7] = pv_mfma(pf, VHI(v3), o_acc[7]);
            __builtin_amdgcn_s_setprio(0);
            barx();                                   // reads of buf[kt&1] done
        }
        w_vm0();                                      // drain dummy stage
        barx();                                       // buffers clean for next qblock

        float lp = l_part;
        lp += __shfl_xor(lp, 16, 64);
        lp += __shfl_xor(lp, 32, 64);
#pragma unroll
        for (int reg = 0; reg < 4; ++reg) {
            float l = __shfl(lp, quad * 4 + reg, 64);
            float inv = 1.f / l;
            int srow = r0 + quad * 4 + reg;
            unsigned short* op = O + (size_t)(b * S_LEN + srow) * HID + h * HDIM;
#pragma unroll
            for (int ct = 0; ct < 8; ++ct)
                op[ct * 16 + l15] = f2bf(o_acc[ct][reg] * inv);
        }
    };

    run_qblock(q);        // 4q+4 tiles
    run_qblock(31 - q);   // 128-4q tiles  (total 132, every block)

#undef ASTAGE
#undef VLO
#undef VHI
}

// ---------------------------------------------------------------- launch
extern "C" void kernel_launch(void* const* d_in, const int* in_sizes, int n_in,
                              void* d_out, int out_size, void* d_ws, size_t ws_size,
                              hipStream_t stream) {
    (void)in_sizes; (void)n_in; (void)out_size; (void)ws_size;
    const float* x  = (const float*)d_in[0];
    const float* wq = (const float*)d_in[2];
    const float* bq = (const float*)d_in[3];
    const float* wk = (const float*)d_in[4];
    const float* bk = (const float*)d_in[5];
    const float* wv = (const float*)d_in[6];
    const float* bv = (const float*)d_in[7];
    const float* wo = (const float*)d_in[8];
    const float* bo = (const float*)d_in[9];
    float* out = (float*)d_out;

    unsigned short* ws = (unsigned short*)d_ws;
    const size_t WSZ = 4194304;
    unsigned short* wqT = ws;                // [0, 4M)   wqT/wkT/wvT contiguous =
    unsigned short* wkT = ws + WSZ;          // [4M, 8M)  fused [6144][2048] B for QKV
    unsigned short* wvT = ws + 2 * WSZ;      // [8M, 12M)
    unsigned short* woT = ws + 3 * WSZ;      // [12M, 16M)
    unsigned short* xb  = ws + 4 * WSZ;      // [16M, 24M)
    unsigned short* Ab  = ws + 4 * WSZ;      // aliases xb (dead after QKV gemm)
    unsigned short* Qb  = ws + 6 * WSZ;      // [24M, 32M)
    unsigned short* Kb  = ws + 8 * WSZ;      // [32M, 40M)  fragment-packed
    unsigned short* Vb  = ws + 10 * WSZ;     // [40M, 48M)  fragment-packed

    convert_all<<<dim3(32, 32, 12), 256, 0, stream>>>(x, wq, wk, wv, wo,
                                                      xb, wqT, wkT, wvT, woT);
    gemm8p<<<dim3(384), 512, 0, stream>>>(xb, wqT, bq, bk, bv, Qb, Kb, Vb);
    attn_kernel<<<dim3(512), 256, 0, stream>>>(Qb, Kb, Vb, Ab);
    gemmO<<<dim3(256), 512, 0, stream>>>(Ab, woT, bo, out);
}

// Round 14
// 391.008 us; speedup vs baseline: 1.0503x; 1.0075x over previous
//
#include <hip/hip_runtime.h>

// CausalSelfAttention: B=2, S=2048, H=2048, NH=16, HD=128. f32 in/out, bf16 MFMA inside.
// R21 = best-of-breed composition (no new structure):
//   QKV:     R14 gemmT<1,3>  (117.3-118.2us measured in R19b run; 873 TF; best of
//            6 schedule families tested R10-R20 — 8-phase@256^2 hits 47% while-running
//            MfmaUtil but loses to the unavoidable 1.5-round grid, net 139us)
//   attn:    R17 pair-balanced block-shared-KV (best totals 394.7/393.9 carried it;
//            R16/R19 variants both regressed)
//   outproj: R14 gemmT<0,2> (grid 256 = 1 exact round)
//   converts: fused convert_all (verified 3x)
// Same-run substitution vs R20: gemm8p(139us) -> gemmT(118us), predict ~373-385 total.

using bf16x8 = __attribute__((ext_vector_type(8))) short;
using bf16x4 = __attribute__((ext_vector_type(4))) short;
using f32x4  = __attribute__((ext_vector_type(4))) float;

#define S_LEN 2048
#define NHEAD 16
#define HDIM  128
#define HID   2048

__device__ __forceinline__ unsigned short f2bf(float f) {
    unsigned int u = __float_as_uint(f);
    u += 0x7fffu + ((u >> 16) & 1u);   // round-to-nearest-even
    return (unsigned short)(u >> 16);
}
__device__ __forceinline__ void gl2lds16(const void* g, void* l) {
    __builtin_amdgcn_global_load_lds(
        (const __attribute__((address_space(1))) void*)g,
        (__attribute__((address_space(3))) void*)l, 16, 0, 0);
}

// 16x16x16 bf16 MFMA, device-guarded (host pass must not reference the builtin).
__device__ __forceinline__ f32x4 pv_mfma(bf16x4 a, bf16x4 b, f32x4 c) {
#if defined(__HIP_DEVICE_COMPILE__)
#if __has_builtin(__builtin_amdgcn_mfma_f32_16x16x16bf16_1k)
    return __builtin_amdgcn_mfma_f32_16x16x16bf16_1k(a, b, c, 0, 0, 0);
#else
    asm("v_mfma_f32_16x16x16_bf16 %0, %1, %2, %0" : "+v"(c) : "v"(a), "v"(b));
    return c;
#endif
#else
    (void)a; (void)b;
    return c;
#endif
}

// --------------------------------- fused converts: x f32->bf16, weights f32->bf16^T
// grid (32, 32, 12): z<4 -> weight transpose tile; z>=4 -> x chunk. (verified R18/R19b/R20)
__global__ void convert_all(const float* __restrict__ x,
                            const float* __restrict__ w0, const float* __restrict__ w1,
                            const float* __restrict__ w2, const float* __restrict__ w3,
                            unsigned short* __restrict__ xb,
                            unsigned short* __restrict__ t0, unsigned short* __restrict__ t1,
                            unsigned short* __restrict__ t2, unsigned short* __restrict__ t3) {
    int z = blockIdx.z;
    if (z >= 4) {
        int lin = (z - 4) * 1024 + blockIdx.y * 32 + blockIdx.x;   // 0..8191
        int i = (lin * 256 + threadIdx.x) * 4;
        float4 v = *(const float4*)(x + i);
        ushort4 o;
        o.x = f2bf(v.x); o.y = f2bf(v.y); o.z = f2bf(v.z); o.w = f2bf(v.w);
        *(ushort4*)(xb + i) = o;
        return;
    }
    __shared__ float tile[64][65];
    const float* src = (z == 0) ? w0 : (z == 1) ? w1 : (z == 2) ? w2 : w3;
    unsigned short* dst = (z == 0) ? t0 : (z == 1) ? t1 : (z == 2) ? t2 : t3;
    int r0 = blockIdx.y * 64, c0 = blockIdx.x * 64;
    int t = threadIdx.x;
    for (int i = t; i < 64 * 64; i += 256) {
        int r = i >> 6, c = i & 63;
        tile[r][c] = src[(size_t)(r0 + r) * HID + c0 + c];
    }
    __syncthreads();
    for (int i = t; i < 64 * 64; i += 256) {
        int r = i & 63, c = i >> 6;
        dst[(size_t)(c0 + c) * HID + r0 + r] = f2bf(tile[r][c]);
    }
}

// ---- counted waits (asm literals need compile-time dispatch) -----------------
__device__ __forceinline__ void sched0() { __builtin_amdgcn_sched_barrier(0); }
__device__ __forceinline__ void w_lgkm4() { asm volatile("s_waitcnt lgkmcnt(4)" ::: "memory"); sched0(); }
__device__ __forceinline__ void w_lgkm0() { asm volatile("s_waitcnt lgkmcnt(0)" ::: "memory"); sched0(); }
template <int NJ> __device__ __forceinline__ void w_lgkm_4nj() {
    if constexpr (NJ == 3) { asm volatile("s_waitcnt lgkmcnt(7)" ::: "memory"); }
    else                   { asm volatile("s_waitcnt lgkmcnt(6)" ::: "memory"); }
    sched0();
}
template <int NJ> __device__ __forceinline__ void w_vm_ns() {
    if constexpr (NJ == 3) { asm volatile("s_waitcnt vmcnt(7)" ::: "memory"); }
    else                   { asm volatile("s_waitcnt vmcnt(6)" ::: "memory"); }
    sched0();
}
__device__ __forceinline__ void w_vm2() { asm volatile("s_waitcnt vmcnt(2)" ::: "memory"); sched0(); }
__device__ __forceinline__ void w_vm0() { asm volatile("s_waitcnt vmcnt(0)" ::: "memory"); sched0(); }
__device__ __forceinline__ void barx() {
    asm volatile("" ::: "memory");
    __builtin_amdgcn_s_barrier();
    asm volatile("" ::: "memory");
}

// ---------------------------------------------------------------- GEMM 256xBN (R14, frozen)
// C[4096][N] = A @ Bt^T + bias; A,Bt bf16, fp32 acc. BN = NJ*64.
// MODE 1: fused QKV, N=6144, Bt0 = contiguous [6144][2048]. NJ=3 -> grid 512 (2 rounds).
// MODE 0: out-proj, N=2048, f32 out. NJ=2 -> grid 256 (1 round).
template <int MODE, int NJ>
__launch_bounds__(512, 2)
__global__ void gemmT(const unsigned short* __restrict__ A,
                      const unsigned short* __restrict__ Bt0,
                      const float* __restrict__ bias0,
                      const float* __restrict__ bias1,
                      const float* __restrict__ bias2,
                      unsigned short* __restrict__ C0,
                      unsigned short* __restrict__ C1,
                      unsigned short* __restrict__ C2,
                      float* __restrict__ Cf) {
    constexpr int BN = NJ * 64;
    __shared__ __align__(16) unsigned short lds[2 * 16384 + 2 * NJ * 4096];
    unsigned short* const A0 = lds;
    unsigned short* const A1 = lds + 16384;
    unsigned short* const B0 = lds + 32768;
    unsigned short* const B1 = lds + 32768 + NJ * 4096;

    const int CPX = (MODE == 1) ? 64 : 32;      // blocks per XCD (bijective: nwg%8==0)
    int vb = (blockIdx.x & 7) * CPX + (blockIdx.x >> 3);
    int m0  = (vb & 15) * 256;
    int n0g = (vb >> 4) * BN;                   // fused col (0..6143 / 0..2047)

    int tid = threadIdx.x;
    int lane = tid & 63;
    int wv_ = tid >> 6;
    int wr = wv_ >> 2, wc = wv_ & 3;            // 2x4 wave grid; wave tile 128 x (NJ*16)
    int l15 = lane & 15, quad = lane >> 4;

    int tr = tid >> 3;
    int tc = ((tid & 7) ^ (tr & 7)) << 3;
    const unsigned short* gA = A   + (size_t)(m0  + tr) * HID + tc;
    const unsigned short* gB = Bt0 + (size_t)(n0g + tr) * HID + tc;
    const int td8 = tid * 8;

    int arow0 = (wr * 128 + l15) * 64;          // + mi*1024
    int brow0 = (wc * (16 * NJ) + l15) * 64;    // + nj*1024
    int sw0 = ((quad ^ (l15 & 7)) << 3);        // kk=0
    int sw1 = (((4 + quad) ^ (l15 & 7)) << 3);  // kk=1

    f32x4 acc[8][NJ];
#pragma unroll
    for (int i = 0; i < 8; ++i)
#pragma unroll
        for (int j = 0; j < NJ; ++j) acc[i][j] = (f32x4){0.f, 0.f, 0.f, 0.f};

    bf16x8 aX[4], aY[4], b0v[NJ], b1v[NJ];

#define STAGE(kt, AD, BD) do { int _kc = (kt) * 64;                          \
    gl2lds16(gA + _kc,             (AD) + td8);                              \
    gl2lds16(gA + 64 * HID + _kc,  (AD) + 4096 + td8);                       \
    gl2lds16(gA + 128 * HID + _kc, (AD) + 8192 + td8);                       \
    gl2lds16(gA + 192 * HID + _kc, (AD) + 12288 + td8);                      \
    _Pragma("unroll")                                                        \
    for (int _r = 0; _r < NJ; ++_r)                                          \
        gl2lds16(gB + (size_t)(_r * 64) * HID + _kc, (BD) + _r * 4096 + td8); } while (0)

#define LDA4(dst, AD, QB, SW) do {                                           \
    dst[0] = *(const bf16x8*)((AD) + arow0 + ((QB) + 0) * 1024 + (SW));      \
    dst[1] = *(const bf16x8*)((AD) + arow0 + ((QB) + 1) * 1024 + (SW));      \
    dst[2] = *(const bf16x8*)((AD) + arow0 + ((QB) + 2) * 1024 + (SW));      \
    dst[3] = *(const bf16x8*)((AD) + arow0 + ((QB) + 3) * 1024 + (SW)); } while (0)

#define LDB(dst, BD, SW) do {                                                \
    _Pragma("unroll")                                                        \
    for (int _n = 0; _n < NJ; ++_n)                                          \
        dst[_n] = *(const bf16x8*)((BD) + brow0 + _n * 1024 + (SW)); } while (0)

#define MF(Q, a, b) do {                                                     \
    __builtin_amdgcn_s_setprio(1);                                           \
    _Pragma("unroll")                                                        \
    for (int mi = 0; mi < 4; ++mi)                                           \
        _Pragma("unroll")                                                    \
        for (int nj = 0; nj < NJ; ++nj)                                      \
            acc[(Q) * 4 + mi][nj] =                                          \
                __builtin_amdgcn_mfma_f32_16x16x32_bf16(a[mi], b[nj],        \
                                                        acc[(Q) * 4 + mi][nj], 0, 0, 0); \
    __builtin_amdgcn_s_setprio(0); } while (0)

#define TILE(AD, BD, AN, BN_, ks) do {                                       \
    LDA4(aY, AD, 4, sw0);            /* ds: 8+NJ */                          \
    w_lgkm4();                       /* aX,b0v ready; aY rides */            \
    MF(0, aX, b0v);                                                          \
    LDA4(aX, AD, 0, sw1);                                                    \
    LDB(b1v, BD, sw1);               /* ds: aY4 + 4+NJ */                    \
    w_lgkm_4nj<NJ>();                /* aY ready */                          \
    MF(1, aY, b0v);                                                          \
    LDA4(aY, AD, 4, sw1);            /* ds: 8+NJ */                          \
    w_lgkm4();                       /* aX,b1v ready */                      \
    MF(0, aX, b1v);                                                          \
    w_lgkm0();                       /* all my (AD,BD) reads done */         \
    barx();                          /* all waves done reading (AD,BD) */    \
    STAGE(ks, AD, BD);               /* vm: old 4+NJ + new 4+NJ */           \
    w_vm_ns<NJ>();                   /* stage(t+1 -> AN,BN_) complete */     \
    barx();                          /* (AN,BN_) certified for all */        \
    LDA4(aX, AN, 0, sw0);                                                    \
    LDB(b0v, BN_, sw0);              /* next-tile kk0 reads in flight */     \
    sched0();                                                                \
    MF(1, aY, b1v);                  /* rides over next-tile reads */        \
} while (0)

    STAGE(0, A0, B0);
    STAGE(1, A1, B1);
    w_vm_ns<NJ>();
    barx();
    LDA4(aX, A0, 0, sw0);
    LDB(b0v, B0, sw0);

    for (int t = 0; t < 32; t += 2) {
        TILE(A0, B0, A1, B1, (t + 2 < 32) ? t + 2 : 31);
        TILE(A1, B1, A0, B0, (t + 3 < 32) ? t + 3 : 31);
    }
    asm volatile("s_waitcnt vmcnt(0) lgkmcnt(0)" ::: "memory");

#undef TILE
#undef STAGE
#undef LDA4
#undef LDB
#undef MF

    // ---- epilogue (pack formulas verbatim; z selected per column for fused tiles)
#pragma unroll
    for (int j = 0; j < NJ; ++j) {
        int n = n0g + wc * (16 * NJ) + j * 16 + l15;    // fused col
        int zj = (MODE == 1) ? (n >> 11) : 0;
        int nn = (MODE == 1) ? (n & 2047) : n;
        float bn = (MODE == 1)
                     ? ((zj == 0) ? bias0[nn] : (zj == 1) ? bias1[nn] : bias2[nn])
                     : bias0[nn];
        unsigned short* Cz = (zj == 0) ? C0 : (zj == 1) ? C1 : C2;
#pragma unroll
        for (int i = 0; i < 8; ++i) {
            int mb = m0 + wr * 128 + i * 16 + quad * 4;   // base row, regs = mb..mb+3
            if (MODE == 1 && zj == 2) {
                // V-pack: 4 regs = 4 consecutive keys (e=0..3) -> one ushort4.
                int b = mb >> 11, s = mb & 2047, h = nn >> 7, d = nn & 127;
                int kt = s >> 4, qv = (s >> 2) & 3, ct = d >> 4, lv = d & 15;
                size_t addr = ((((size_t)((b << 4) + h) * 128 + kt) * 4 + (ct >> 1)) * 4 + qv) * 128
                              + lv * 8 + (ct & 1) * 4;
                ushort4 o;
                o.x = f2bf(acc[i][j][0] + bn);
                o.y = f2bf(acc[i][j][1] + bn);
                o.z = f2bf(acc[i][j][2] + bn);
                o.w = f2bf(acc[i][j][3] + bn);
                *(ushort4*)&Cz[addr] = o;
            } else {
#pragma unroll
                for (int reg = 0; reg < 4; ++reg) {
                    int m = mb + reg;
                    float v = acc[i][j][reg] + bn;
                    if (MODE == 0) {
                        Cf[(size_t)m * HID + nn] = v;
                    } else {
                        int b = m >> 11, s = m & 2047, h = nn >> 7, d = nn & 127;
                        if (zj == 1) {
                            // K-pack: key=s -> (kt, lk); d -> (kk, qk, e)
                            int kt = s >> 4, lk = s & 15, kk = d >> 5, qk = (d >> 3) & 3, e = d & 7;
                            size_t addr = ((((size_t)((b << 4) + h) * 128 + kt) * 4 + kk) * 4 + qk) * 128
                                          + lk * 8 + e;
                            Cz[addr] = f2bf(v);
                        } else {
                            Cz[(size_t)(((b << 4) + h) * S_LEN + s) * HDIM + d] = f2bf(v);
                        }
                    }
                }
            }
        }
    }
}

// ---------------------------------------------------------------- flash attention (R17, best)
// Block = 4 waves = 64-row Q-block. K/V tile (8KB) staged once per block into LDS
// (dbuf, counted vmcnt(2)). Q-block pair (q, 31-q) -> exactly 132 tiles per block.
__launch_bounds__(256, 2)
__global__ void attn_kernel(const unsigned short* __restrict__ Qg,
                            const unsigned short* __restrict__ Kp,
                            const unsigned short* __restrict__ Vp,
                            unsigned short* __restrict__ O) {
    __shared__ __align__(16) unsigned short kv[2][4096];   // [buf][K:0..2048 | V:2048..4096]

    int linear = blockIdx.x;                  // 0..511
    int xcd = linear & 7;
    int u = linear >> 3;                      // 0..63
    int bh = xcd * 4 + (u & 3);               // 4 bh per XCD (K/V 4MB ~ L2)
    int q = u >> 2;                           // 0..15 -> pair (q, 31-q)
    int b = bh >> 4, h = bh & 15;

    int tid = threadIdx.x, lane = tid & 63, w = tid >> 6;
    int l15 = lane & 15, quad = lane >> 4;

    const unsigned short* Qb = Qg + (size_t)bh * (S_LEN * HDIM);
    const unsigned short* Kg = Kp + (size_t)bh * 262144;
    const unsigned short* Vg = Vp + (size_t)bh * 262144;
    const float k2 = 0.08838834764831845f * 1.4426950408889634f;  // scale*log2(e)

    const int frag = quad * 128 + l15 * 8;    // in-tile fragment offset (elems)
    const int td8 = tid * 8;                  // staging offset: tid*16B

#define VLO(x) __builtin_shufflevector(x, x, 0, 1, 2, 3)
#define VHI(x) __builtin_shufflevector(x, x, 4, 5, 6, 7)
#define ASTAGE(kt, bf) do { size_t _g = (size_t)(kt) * 2048 + td8;             \
    gl2lds16(Kg + _g, &kv[bf][td8]);                                           \
    gl2lds16(Vg + _g, &kv[bf][2048 + td8]); } while (0)

    auto run_qblock = [&](int qb) {
        int s  = 4 * qb + w;                  // my strip (diagonal tile = s)
        int r0 = s * 16;
        int N  = 4 * qb + 4;                  // staged tiles (block-uniform)

        bf16x8 qf[4];
#pragma unroll
        for (int kk = 0; kk < 4; ++kk)
            qf[kk] = *(const bf16x8*)&Qb[(size_t)(r0 + l15) * HDIM + kk * 32 + quad * 8];

        f32x4 o_acc[8];
#pragma unroll
        for (int c = 0; c < 8; ++c) o_acc[c] = (f32x4){0.f, 0.f, 0.f, 0.f};
        float l_part = 0.f;

        ASTAGE(0, 0);
        for (int kt = 0; kt < N; ++kt) {
            int nk = (kt + 1 < N) ? kt + 1 : kt;      // uniform dummy re-stage at end
            ASTAGE(nk, (kt + 1) & 1);
            w_vm2();                                  // my 2 ops of stage(kt) done
            barx();                                   // all waves: tile kt staged

            const unsigned short* KL = &kv[kt & 1][frag];
            const unsigned short* VL = &kv[kt & 1][2048 + frag];
            bf16x8 kb0 = *(const bf16x8*)(KL);
            bf16x8 kb1 = *(const bf16x8*)(KL + 512);
            bf16x8 kb2 = *(const bf16x8*)(KL + 1024);
            bf16x8 kb3 = *(const bf16x8*)(KL + 1536);
            bf16x8 v0 = *(const bf16x8*)(VL);
            bf16x8 v1 = *(const bf16x8*)(VL + 512);
            bf16x8 v2 = *(const bf16x8*)(VL + 1024);
            bf16x8 v3 = *(const bf16x8*)(VL + 1536);

            f32x4 st0 = (f32x4){0.f, 0.f, 0.f, 0.f};
            f32x4 st1 = (f32x4){0.f, 0.f, 0.f, 0.f};
            __builtin_amdgcn_s_setprio(1);
            st0 = __builtin_amdgcn_mfma_f32_16x16x32_bf16(kb0, qf[0], st0, 0, 0, 0);
            st1 = __builtin_amdgcn_mfma_f32_16x16x32_bf16(kb1, qf[1], st1, 0, 0, 0);
            st0 = __builtin_amdgcn_mfma_f32_16x16x32_bf16(kb2, qf[2], st0, 0, 0, 0);
            st1 = __builtin_amdgcn_mfma_f32_16x16x32_bf16(kb3, qf[3], st1, 0, 0, 0);
            __builtin_amdgcn_s_setprio(0);
            f32x4 stv = st0 + st1;

            float p0, p1, p2, p3;
            int doff = kt - s;                        // wave-uniform
            if (doff >= 0) {
                int d16 = doff << 4;
                p0 = (d16 + quad * 4 + 0 <= l15) ? exp2f(stv[0] * k2) : 0.f;
                p1 = (d16 + quad * 4 + 1 <= l15) ? exp2f(stv[1] * k2) : 0.f;
                p2 = (d16 + quad * 4 + 2 <= l15) ? exp2f(stv[2] * k2) : 0.f;
                p3 = (d16 + quad * 4 + 3 <= l15) ? exp2f(stv[3] * k2) : 0.f;
            } else {
                p0 = exp2f(stv[0] * k2); p1 = exp2f(stv[1] * k2);
                p2 = exp2f(stv[2] * k2); p3 = exp2f(stv[3] * k2);
            }
            l_part += (p0 + p1) + (p2 + p3);

            bf16x4 pf;
            pf[0] = (short)f2bf(p0); pf[1] = (short)f2bf(p1);
            pf[2] = (short)f2bf(p2); pf[3] = (short)f2bf(p3);

            __builtin_amdgcn_s_setprio(1);
            o_acc[0] = pv_mfma(pf, VLO(v0), o_acc[0]);
            o_acc[1] = pv_mfma(pf, VHI(v0), o_acc[1]);
            o_acc[2] = pv_mfma(pf, VLO(v1), o_acc[2]);
            o_acc[3] = pv_mfma(pf, VHI(v1), o_acc[3]);
            o_acc[4] = pv_mfma(pf, VLO(v2), o_acc[4]);
            o_acc[5] = pv_mfma(pf, VHI(v2), o_acc[5]);
            o_acc[6] = pv_mfma(pf, VLO(v3), o_acc[6]);
            o_acc[7] = pv_mfma(pf, VHI(v3), o_acc[7]);
            __builtin_amdgcn_s_setprio(0);
            barx();                                   // reads of buf[kt&1] done
        }
        w_vm0();                                      // drain dummy stage
        barx();                                       // buffers clean for next qblock

        float lp = l_part;
        lp += __shfl_xor(lp, 16, 64);
        lp += __shfl_xor(lp, 32, 64);
#pragma unroll
        for (int reg = 0; reg < 4; ++reg) {
            float l = __shfl(lp, quad * 4 + reg, 64);
            float inv = 1.f / l;
            int srow = r0 + quad * 4 + reg;
            unsigned short* op = O + (size_t)(b * S_LEN + srow) * HID + h * HDIM;
#pragma unroll
            for (int ct = 0; ct < 8; ++ct)
                op[ct * 16 + l15] = f2bf(o_acc[ct][reg] * inv);
        }
    };

    run_qblock(q);        // 4q+4 tiles
    run_qblock(31 - q);   // 128-4q tiles  (total 132, every block)

#undef ASTAGE
#undef VLO
#undef VHI
}

// ---------------------------------------------------------------- launch
extern "C" void kernel_launch(void* const* d_in, const int* in_sizes, int n_in,
                              void* d_out, int out_size, void* d_ws, size_t ws_size,
                              hipStream_t stream) {
    (void)in_sizes; (void)n_in; (void)out_size; (void)ws_size;
    const float* x  = (const float*)d_in[0];
    const float* wq = (const float*)d_in[2];
    const float* bq = (const float*)d_in[3];
    const float* wk = (const float*)d_in[4];
    const float* bk = (const float*)d_in[5];
    const float* wv = (const float*)d_in[6];
    const float* bv = (const float*)d_in[7];
    const float* wo = (const float*)d_in[8];
    const float* bo = (const float*)d_in[9];
    float* out = (float*)d_out;

    unsigned short* ws = (unsigned short*)d_ws;
    const size_t WSZ = 4194304;
    unsigned short* wqT = ws;                // [0, 4M)   wqT/wkT/wvT contiguous =
    unsigned short* wkT = ws + WSZ;          // [4M, 8M)  fused [6144][2048] B for QKV
    unsigned short* wvT = ws + 2 * WSZ;      // [8M, 12M)
    unsigned short* woT = ws + 3 * WSZ;      // [12M, 16M)
    unsigned short* xb  = ws + 4 * WSZ;      // [16M, 24M)
    unsigned short* Ab  = ws + 4 * WSZ;      // aliases xb (dead after QKV gemm)
    unsigned short* Qb  = ws + 6 * WSZ;      // [24M, 32M)
    unsigned short* Kb  = ws + 8 * WSZ;      // [32M, 40M)  fragment-packed
    unsigned short* Vb  = ws + 10 * WSZ;     // [40M, 48M)  fragment-packed

    convert_all<<<dim3(32, 32, 12), 256, 0, stream>>>(x, wq, wk, wv, wo,
                                                      xb, wqT, wkT, wvT, woT);
    gemmT<1, 3><<<dim3(512), 512, 0, stream>>>(xb, wqT, bq, bk, bv,
                                               Qb, Kb, Vb, nullptr);
    attn_kernel<<<dim3(512), 256, 0, stream>>>(Qb, Kb, Vb, Ab);
    gemmT<0, 2><<<dim3(256), 512, 0, stream>>>(Ab, woT, bo, nullptr, nullptr,
                                               nullptr, nullptr, nullptr, out);
}

// Round 16
// 371.709 us; speedup vs baseline: 1.1049x; 1.0519x over previous
//
#include <hip/hip_runtime.h>

// CausalSelfAttention: B=2, S=2048, H=2048, NH=16, HD=128. f32 in/out, bf16 MFMA inside.
// R23 = R22 with the gemm8q LDS race FIXED. R22 failed (absmax 0.43) because the
// phase-read "half" (hm*64 within each wave's 128-row strip) didn't match the
// staging half (contiguous 128 rows): ph3's stage of A0-lo overwrote rows 64..127
// one phase before ph4 read them. R23 remaps A fragments so hm selects the
// CONTIGUOUS staging half: rows = hm*128 + wr*64 + mi*16 + l15. A-lo is now fully
// read by ALL waves at ph1/ph2 -> free when staged at ph3; ph4's reads (rows
// 128..255) are disjoint from ph3's stage. B fully read by ph2; staged ph4/ph5.
// Zero read/write overlap anywhere (ledger + region audit). vm FIFO unchanged:
// 4->7->9->11, vm4 at ph4/ph8 completes exactly the next tile's 7 ops, never drains.
// Epilogue row map updated: mb = m0 + (i>>2)*128 + wr*64 + (i&3)*16 + quad*4.
// attn R17 / outproj gemmT<0,2> / convert_all: frozen from R21 (best passing, 391.0us).

using bf16x8 = __attribute__((ext_vector_type(8))) short;
using bf16x4 = __attribute__((ext_vector_type(4))) short;
using f32x4  = __attribute__((ext_vector_type(4))) float;

#define S_LEN 2048
#define NHEAD 16
#define HDIM  128
#define HID   2048

__device__ __forceinline__ unsigned short f2bf(float f) {
    unsigned int u = __float_as_uint(f);
    u += 0x7fffu + ((u >> 16) & 1u);   // round-to-nearest-even
    return (unsigned short)(u >> 16);
}
__device__ __forceinline__ void gl2lds16(const void* g, void* l) {
    __builtin_amdgcn_global_load_lds(
        (const __attribute__((address_space(1))) void*)g,
        (__attribute__((address_space(3))) void*)l, 16, 0, 0);
}

// 16x16x16 bf16 MFMA, device-guarded (host pass must not reference the builtin).
__device__ __forceinline__ f32x4 pv_mfma(bf16x4 a, bf16x4 b, f32x4 c) {
#if defined(__HIP_DEVICE_COMPILE__)
#if __has_builtin(__builtin_amdgcn_mfma_f32_16x16x16bf16_1k)
    return __builtin_amdgcn_mfma_f32_16x16x16bf16_1k(a, b, c, 0, 0, 0);
#else
    asm("v_mfma_f32_16x16x16_bf16 %0, %1, %2, %0" : "+v"(c) : "v"(a), "v"(b));
    return c;
#endif
#else
    (void)a; (void)b;
    return c;
#endif
}

// --------------------------------- fused converts: x f32->bf16, weights f32->bf16^T
__global__ void convert_all(const float* __restrict__ x,
                            const float* __restrict__ w0, const float* __restrict__ w1,
                            const float* __restrict__ w2, const float* __restrict__ w3,
                            unsigned short* __restrict__ xb,
                            unsigned short* __restrict__ t0, unsigned short* __restrict__ t1,
                            unsigned short* __restrict__ t2, unsigned short* __restrict__ t3) {
    int z = blockIdx.z;
    if (z >= 4) {
        int lin = (z - 4) * 1024 + blockIdx.y * 32 + blockIdx.x;   // 0..8191
        int i = (lin * 256 + threadIdx.x) * 4;
        float4 v = *(const float4*)(x + i);
        ushort4 o;
        o.x = f2bf(v.x); o.y = f2bf(v.y); o.z = f2bf(v.z); o.w = f2bf(v.w);
        *(ushort4*)(xb + i) = o;
        return;
    }
    __shared__ float tile[64][65];
    const float* src = (z == 0) ? w0 : (z == 1) ? w1 : (z == 2) ? w2 : w3;
    unsigned short* dst = (z == 0) ? t0 : (z == 1) ? t1 : (z == 2) ? t2 : t3;
    int r0 = blockIdx.y * 64, c0 = blockIdx.x * 64;
    int t = threadIdx.x;
    for (int i = t; i < 64 * 64; i += 256) {
        int r = i >> 6, c = i & 63;
        tile[r][c] = src[(size_t)(r0 + r) * HID + c0 + c];
    }
    __syncthreads();
    for (int i = t; i < 64 * 64; i += 256) {
        int r = i & 63, c = i >> 6;
        dst[(size_t)(c0 + c) * HID + r0 + r] = f2bf(tile[r][c]);
    }
}

// ---- counted waits -----------------------------------------------------------
__device__ __forceinline__ void sched0() { __builtin_amdgcn_sched_barrier(0); }
__device__ __forceinline__ void w_lgkm4() { asm volatile("s_waitcnt lgkmcnt(4)" ::: "memory"); sched0(); }
__device__ __forceinline__ void w_lgkm0() { asm volatile("s_waitcnt lgkmcnt(0)" ::: "memory"); sched0(); }
template <int NJ> __device__ __forceinline__ void w_lgkm_4nj() {
    if constexpr (NJ == 3) { asm volatile("s_waitcnt lgkmcnt(7)" ::: "memory"); }
    else                   { asm volatile("s_waitcnt lgkmcnt(6)" ::: "memory"); }
    sched0();
}
template <int NJ> __device__ __forceinline__ void w_vm_ns() {
    if constexpr (NJ == 3) { asm volatile("s_waitcnt vmcnt(7)" ::: "memory"); }
    else                   { asm volatile("s_waitcnt vmcnt(6)" ::: "memory"); }
    sched0();
}
__device__ __forceinline__ void w_vm4() { asm volatile("s_waitcnt vmcnt(4)" ::: "memory"); sched0(); }
__device__ __forceinline__ void w_vm2() { asm volatile("s_waitcnt vmcnt(2)" ::: "memory"); sched0(); }
__device__ __forceinline__ void w_vm0() { asm volatile("s_waitcnt vmcnt(0)" ::: "memory"); sched0(); }
__device__ __forceinline__ void barx() {
    asm volatile("" ::: "memory");
    __builtin_amdgcn_s_barrier();
    asm volatile("" ::: "memory");
}

// ---------------------------------------------------------------- QKV GEMM 8-phase (R23)
// C[4096][6144] = A @ Bt^T + bias (fused QKV, Bt = contiguous [6144][2048]).
// 256x192 tile, BK=64, 8 waves 2x4, LDS 112KB, grid 512 = 2 exact rounds.
// A fragment rows = hm*128 + wr*64 + mi*16 + l15 (hm = CONTIGUOUS staging half).
__launch_bounds__(512, 2)
__global__ void gemm8q(const unsigned short* __restrict__ A,
                       const unsigned short* __restrict__ Bt,
                       const float* __restrict__ bias0,
                       const float* __restrict__ bias1,
                       const float* __restrict__ bias2,
                       unsigned short* __restrict__ C0,
                       unsigned short* __restrict__ C1,
                       unsigned short* __restrict__ C2) {
    __shared__ __align__(16) unsigned short lds[57344];   // 112KB
    unsigned short* const A0 = lds;            // A: 256x64 = 16384 elems per buf
    unsigned short* const A1 = lds + 16384;
    unsigned short* const B0 = lds + 32768;    // B: 192x64 = 12288 elems per buf
    unsigned short* const B1 = lds + 45056;

    int vb = (blockIdx.x & 7) * 64 + (blockIdx.x >> 3);   // 512 blocks, bijective
    int m0  = (vb & 15) * 256;
    int n0g = (vb >> 4) * 192;

    int tid = threadIdx.x;
    int lane = tid & 63;
    int wv_ = tid >> 6;
    int wr = wv_ >> 2, wc = wv_ & 3;            // 2x4 wave grid
    int l15 = lane & 15, quad = lane >> 4;

    // staging: 512 thr x 16B = 64 rows/issue. A-half = 2 issues, B-third = 1 issue.
    // T2 pre-swizzled source (verified): LDS 16B-slot s of row r holds col-slot s^(r&7).
    int tr = tid >> 3;
    int tc = ((tid & 7) ^ (tr & 7)) << 3;
    const unsigned short* gA = A  + (size_t)(m0  + tr) * HID + tc;
    const unsigned short* gB = Bt + (size_t)(n0g + tr) * HID + tc;
    const int td8 = tid * 8;

    int arow0 = (wr * 64 + l15) * 64;           // + hm*8192 + mi*1024 (rows: hm*128+wr*64+mi*16+l15)
    int brow0 = (wc * 48 + l15) * 64;           // + nj*1024
    int swz[2] = { ((quad ^ (l15 & 7)) << 3), (((4 + quad) ^ (l15 & 7)) << 3) };

    f32x4 acc[8][3];
#pragma unroll
    for (int i = 0; i < 8; ++i)
#pragma unroll
        for (int j = 0; j < 3; ++j) acc[i][j] = (f32x4){0.f, 0.f, 0.f, 0.f};

    bf16x8 av[4];         // per-phase A frags
    bf16x8 bv[2][3];      // [kk][nj], read ph1/ph2, reused ph3/ph4

#define SGA(kt, half, AD) do {                                               \
    size_t _g = (size_t)((half) * 128) * HID + (size_t)(kt) * 64;            \
    gl2lds16(gA + _g,            (AD) + (half) * 8192 + td8);                \
    gl2lds16(gA + _g + 64 * HID, (AD) + (half) * 8192 + 4096 + td8); } while (0)

#define SGB3(kt, third, BD) do {                                             \
    size_t _g = (size_t)((third) * 64) * HID + (size_t)(kt) * 64;            \
    gl2lds16(gB + _g, (BD) + (third) * 4096 + td8); } while (0)

#define RDA(AD, hm, kk) do {                                                 \
    _Pragma("unroll")                                                        \
    for (int mi = 0; mi < 4; ++mi)                                           \
        av[mi] = *(const bf16x8*)((AD) + arow0 + (hm) * 8192                 \
                                  + mi * 1024 + swz[kk]); } while (0)

#define RDB(BD, kk) do {                                                     \
    _Pragma("unroll")                                                        \
    for (int nj = 0; nj < 3; ++nj)                                           \
        bv[kk][nj] = *(const bf16x8*)((BD) + brow0 + nj * 1024 + swz[kk]); } while (0)

#define MFQ(hm, kk) do {                                                     \
    __builtin_amdgcn_s_setprio(1);                                           \
    _Pragma("unroll")                                                        \
    for (int mi = 0; mi < 4; ++mi)                                           \
        _Pragma("unroll")                                                    \
        for (int nj = 0; nj < 3; ++nj)                                       \
            acc[(hm) * 4 + mi][nj] =                                         \
                __builtin_amdgcn_mfma_f32_16x16x32_bf16(av[mi], bv[kk][nj],  \
                    acc[(hm) * 4 + mi][nj], 0, 0, 0);                        \
    __builtin_amdgcn_s_setprio(0); sched0(); } while (0)

    // ---- prologue: tile0 full (7 ops) + tile1 {A-lo, B thirds 0,1} (4 ops) = 11;
    // vm4 completes oldest 7 = tile0 ✓, leaves 4 in flight.
    SGA(0, 0, A0); SGA(0, 1, A0);
    SGB3(0, 0, B0); SGB3(0, 1, B0); SGB3(0, 2, B0);
    SGA(1, 0, A1); SGB3(1, 0, B1); SGB3(1, 1, B1);
    w_vm4();
    barx();

    for (int it = 0; it < 16; ++it) {
        int t  = 2 * it;
        int t2 = (t + 2 < 32) ? t + 2 : 31;   // dummy re-stage at tail (never read)
        int t3 = (t + 3 < 32) ? t + 3 : 31;
        // ---- ph1 (A-lo, k0) tile t; stage A1hi + B1t2 (t+1): vm 4->7
        RDA(A0, 0, 0); RDB(B0, 0);            // 7 ds  [rows 0..127 all-wave]
        SGA(t + 1, 1, A1); SGB3(t + 1, 2, B1);
        barx(); w_lgkm0();
        MFQ(0, 0);
        barx();
        // ---- ph2 (A-lo, k1)  [A-lo + all B fully read after this phase]
        RDA(A0, 0, 1); RDB(B0, 1);            // 7
        barx(); w_lgkm0();
        MFQ(0, 1);
        barx();
        // ---- ph3 (A-hi, k0); stage A0lo(t+2): vm 7->9  [disjoint from ph3/ph4 reads]
        RDA(A0, 1, 0);                         // 4  [rows 128..255]
        SGA(t2, 0, A0);
        barx(); w_lgkm0();
        MFQ(1, 0);
        barx();
        // ---- ph4 (A-hi, k1); stage B0 t0,t1 (t+2): vm 9->11; vm4 certifies tile t+1
        RDA(A0, 1, 1);                         // 4  [rows 128..255]
        SGB3(t2, 0, B0); SGB3(t2, 1, B0);
        barx(); w_lgkm0();
        MFQ(1, 1);
        w_vm4();
        barx();
        // ---- ph5 (A-lo, k0) tile t+1; stage A0hi + B0t2 (t+2): vm 4->7
        RDA(A1, 0, 0); RDB(B1, 0);
        SGA(t2, 1, A0); SGB3(t2, 2, B0);
        barx(); w_lgkm0();
        MFQ(0, 0);
        barx();
        // ---- ph6 (A-lo, k1)
        RDA(A1, 0, 1); RDB(B1, 1);
        barx(); w_lgkm0();
        MFQ(0, 1);
        barx();
        // ---- ph7 (A-hi, k0); stage A1lo(t+3): vm 7->9  [A1-lo read done at ph6]
        RDA(A1, 1, 0);
        SGA(t3, 0, A1);
        barx(); w_lgkm0();
        MFQ(1, 0);
        barx();
        // ---- ph8 (A-hi, k1); stage B1 t0,t1 (t+3): vm 9->11; vm4 certifies tile t+2
        RDA(A1, 1, 1);
        SGB3(t3, 0, B1); SGB3(t3, 1, B1);
        barx(); w_lgkm0();
        MFQ(1, 1);
        w_vm4();
        barx();
    }
    asm volatile("s_waitcnt vmcnt(0) lgkmcnt(0)" ::: "memory");

#undef SGA
#undef SGB3
#undef RDA
#undef RDB
#undef MFQ

    // ---- epilogue (pack formulas verbatim; row map: i=(hm*4+mi) -> hm*128+wr*64+mi*16)
#pragma unroll
    for (int j = 0; j < 3; ++j) {
        int n = n0g + wc * 48 + j * 16 + l15;           // fused col
        int zj = n >> 11;
        int nn = n & 2047;
        float bn = (zj == 0) ? bias0[nn] : (zj == 1) ? bias1[nn] : bias2[nn];
        unsigned short* Cz = (zj == 0) ? C0 : (zj == 1) ? C1 : C2;
#pragma unroll
        for (int i = 0; i < 8; ++i) {
            int mb = m0 + (i >> 2) * 128 + wr * 64 + (i & 3) * 16 + quad * 4;
            if (zj == 2) {
                // V-pack: 4 regs = 4 consecutive keys (e=0..3) -> one ushort4.
                int b = mb >> 11, s = mb & 2047, h = nn >> 7, d = nn & 127;
                int kt = s >> 4, qv = (s >> 2) & 3, ct = d >> 4, lv = d & 15;
                size_t addr = ((((size_t)((b << 4) + h) * 128 + kt) * 4 + (ct >> 1)) * 4 + qv) * 128
                              + lv * 8 + (ct & 1) * 4;
                ushort4 o;
                o.x = f2bf(acc[i][j][0] + bn);
                o.y = f2bf(acc[i][j][1] + bn);
                o.z = f2bf(acc[i][j][2] + bn);
                o.w = f2bf(acc[i][j][3] + bn);
                *(ushort4*)&Cz[addr] = o;
            } else {
#pragma unroll
                for (int reg = 0; reg < 4; ++reg) {
                    int m = mb + reg;
                    float v = acc[i][j][reg] + bn;
                    int b = m >> 11, s = m & 2047, h = nn >> 7, d = nn & 127;
                    if (zj == 1) {
                        int kt = s >> 4, lk = s & 15, kk = d >> 5, qk = (d >> 3) & 3, e = d & 7;
                        size_t addr = ((((size_t)((b << 4) + h) * 128 + kt) * 4 + kk) * 4 + qk) * 128
                                      + lk * 8 + e;
                        Cz[addr] = f2bf(v);
                    } else {
                        Cz[(size_t)(((b << 4) + h) * S_LEN + s) * HDIM + d] = f2bf(v);
                    }
                }
            }
        }
    }
}

// ---------------------------------------------------------------- out-proj GEMM (R14, frozen)
template <int MODE, int NJ>
__launch_bounds__(512, 2)
__global__ void gemmT(const unsigned short* __restrict__ A,
                      const unsigned short* __restrict__ Bt0,
                      const float* __restrict__ bias0,
                      float* __restrict__ Cf) {
    __shared__ __align__(16) unsigned short lds[2 * 16384 + 2 * NJ * 4096];
    unsigned short* const A0 = lds;
    unsigned short* const A1 = lds + 16384;
    unsigned short* const B0 = lds + 32768;
    unsigned short* const B1 = lds + 32768 + NJ * 4096;

    int vb = (blockIdx.x & 7) * 32 + (blockIdx.x >> 3);
    int m0  = (vb & 15) * 256;
    int n0g = (vb >> 4) * (NJ * 64);

    int tid = threadIdx.x;
    int lane = tid & 63;
    int wv_ = tid >> 6;
    int wr = wv_ >> 2, wc = wv_ & 3;
    int l15 = lane & 15, quad = lane >> 4;

    int tr = tid >> 3;
    int tc = ((tid & 7) ^ (tr & 7)) << 3;
    const unsigned short* gA = A   + (size_t)(m0  + tr) * HID + tc;
    const unsigned short* gB = Bt0 + (size_t)(n0g + tr) * HID + tc;
    const int td8 = tid * 8;

    int arow0 = (wr * 128 + l15) * 64;
    int brow0 = (wc * (16 * NJ) + l15) * 64;
    int sw0 = ((quad ^ (l15 & 7)) << 3);
    int sw1 = (((4 + quad) ^ (l15 & 7)) << 3);

    f32x4 acc[8][NJ];
#pragma unroll
    for (int i = 0; i < 8; ++i)
#pragma unroll
        for (int j = 0; j < NJ; ++j) acc[i][j] = (f32x4){0.f, 0.f, 0.f, 0.f};

    bf16x8 aX[4], aY[4], b0v[NJ], b1v[NJ];

#define STAGE(kt, AD, BD) do { int _kc = (kt) * 64;                          \
    gl2lds16(gA + _kc,             (AD) + td8);                              \
    gl2lds16(gA + 64 * HID + _kc,  (AD) + 4096 + td8);                       \
    gl2lds16(gA + 128 * HID + _kc, (AD) + 8192 + td8);                       \
    gl2lds16(gA + 192 * HID + _kc, (AD) + 12288 + td8);                      \
    _Pragma("unroll")                                                        \
    for (int _r = 0; _r < NJ; ++_r)                                          \
        gl2lds16(gB + (size_t)(_r * 64) * HID + _kc, (BD) + _r * 4096 + td8); } while (0)

#define LDA4(dst, AD, QB, SW) do {                                           \
    dst[0] = *(const bf16x8*)((AD) + arow0 + ((QB) + 0) * 1024 + (SW));      \
    dst[1] = *(const bf16x8*)((AD) + arow0 + ((QB) + 1) * 1024 + (SW));      \
    dst[2] = *(const bf16x8*)((AD) + arow0 + ((QB) + 2) * 1024 + (SW));      \
    dst[3] = *(const bf16x8*)((AD) + arow0 + ((QB) + 3) * 1024 + (SW)); } while (0)

#define LDB(dst, BD, SW) do {                                                \
    _Pragma("unroll")                                                        \
    for (int _n = 0; _n < NJ; ++_n)                                          \
        dst[_n] = *(const bf16x8*)((BD) + brow0 + _n * 1024 + (SW)); } while (0)

#define MF(Q, a, b) do {                                                     \
    __builtin_amdgcn_s_setprio(1);                                           \
    _Pragma("unroll")                                                        \
    for (int mi = 0; mi < 4; ++mi)                                           \
        _Pragma("unroll")                                                    \
        for (int nj = 0; nj < NJ; ++nj)                                      \
            acc[(Q) * 4 + mi][nj] =                                          \
                __builtin_amdgcn_mfma_f32_16x16x32_bf16(a[mi], b[nj],        \
                                                        acc[(Q) * 4 + mi][nj], 0, 0, 0); \
    __builtin_amdgcn_s_setprio(0); } while (0)

#define TILE(AD, BD, AN, BN_, ks) do {                                       \
    LDA4(aY, AD, 4, sw0);                                                    \
    w_lgkm4();                                                               \
    MF(0, aX, b0v);                                                          \
    LDA4(aX, AD, 0, sw1);                                                    \
    LDB(b1v, BD, sw1);                                                       \
    w_lgkm_4nj<NJ>();                                                        \
    MF(1, aY, b0v);                                                          \
    LDA4(aY, AD, 4, sw1);                                                    \
    w_lgkm4();                                                               \
    MF(0, aX, b1v);                                                          \
    w_lgkm0();                                                               \
    barx();                                                                  \
    STAGE(ks, AD, BD);                                                       \
    w_vm_ns<NJ>();                                                           \
    barx();                                                                  \
    LDA4(aX, AN, 0, sw0);                                                    \
    LDB(b0v, BN_, sw0);                                                      \
    sched0();                                                                \
    MF(1, aY, b1v);                                                          \
} while (0)

    STAGE(0, A0, B0);
    STAGE(1, A1, B1);
    w_vm_ns<NJ>();
    barx();
    LDA4(aX, A0, 0, sw0);
    LDB(b0v, B0, sw0);

    for (int t = 0; t < 32; t += 2) {
        TILE(A0, B0, A1, B1, (t + 2 < 32) ? t + 2 : 31);
        TILE(A1, B1, A0, B0, (t + 3 < 32) ? t + 3 : 31);
    }
    asm volatile("s_waitcnt vmcnt(0) lgkmcnt(0)" ::: "memory");

#undef TILE
#undef STAGE
#undef LDA4
#undef LDB
#undef MF

#pragma unroll
    for (int j = 0; j < NJ; ++j) {
        int n = n0g + wc * (16 * NJ) + j * 16 + l15;
        float bn = bias0[n];
#pragma unroll
        for (int i = 0; i < 8; ++i) {
            int mb = m0 + wr * 128 + i * 16 + quad * 4;
#pragma unroll
            for (int reg = 0; reg < 4; ++reg) {
                int m = mb + reg;
                Cf[(size_t)m * HID + n] = acc[i][j][reg] + bn;
            }
        }
    }
}

// ---------------------------------------------------------------- flash attention (R17, best)
__launch_bounds__(256, 2)
__global__ void attn_kernel(const unsigned short* __restrict__ Qg,
                            const unsigned short* __restrict__ Kp,
                            const unsigned short* __restrict__ Vp,
                            unsigned short* __restrict__ O) {
    __shared__ __align__(16) unsigned short kv[2][4096];   // [buf][K:0..2048 | V:2048..4096]

    int linear = blockIdx.x;                  // 0..511
    int xcd = linear & 7;
    int u = linear >> 3;                      // 0..63
    int bh = xcd * 4 + (u & 3);               // 4 bh per XCD (K/V 4MB ~ L2)
    int q = u >> 2;                           // 0..15 -> pair (q, 31-q)
    int b = bh >> 4, h = bh & 15;

    int tid = threadIdx.x, lane = tid & 63, w = tid >> 6;
    int l15 = lane & 15, quad = lane >> 4;

    const unsigned short* Qb = Qg + (size_t)bh * (S_LEN * HDIM);
    const unsigned short* Kg = Kp + (size_t)bh * 262144;
    const unsigned short* Vg = Vp + (size_t)bh * 262144;
    const float k2 = 0.08838834764831845f * 1.4426950408889634f;  // scale*log2(e)

    const int frag = quad * 128 + l15 * 8;    // in-tile fragment offset (elems)
    const int td8 = tid * 8;                  // staging offset: tid*16B

#define VLO(x) __builtin_shufflevector(x, x, 0, 1, 2, 3)
#define VHI(x) __builtin_shufflevector(x, x, 4, 5, 6, 7)
#define ASTAGE(kt, bf) do { size_t _g = (size_t)(kt) * 2048 + td8;             \
    gl2lds16(Kg + _g, &kv[bf][td8]);                                           \
    gl2lds16(Vg + _g, &kv[bf][2048 + td8]); } while (0)

    auto run_qblock = [&](int qb) {
        int s  = 4 * qb + w;                  // my strip (diagonal tile = s)
        int r0 = s * 16;
        int N  = 4 * qb + 4;                  // staged tiles (block-uniform)

        bf16x8 qf[4];
#pragma unroll
        for (int kk = 0; kk < 4; ++kk)
            qf[kk] = *(const bf16x8*)&Qb[(size_t)(r0 + l15) * HDIM + kk * 32 + quad * 8];

        f32x4 o_acc[8];
#pragma unroll
        for (int c = 0; c < 8; ++c) o_acc[c] = (f32x4){0.f, 0.f, 0.f, 0.f};
        float l_part = 0.f;

        ASTAGE(0, 0);
        for (int kt = 0; kt < N; ++kt) {
            int nk = (kt + 1 < N) ? kt + 1 : kt;      // uniform dummy re-stage at end
            ASTAGE(nk, (kt + 1) & 1);
            w_vm2();                                  // my 2 ops of stage(kt) done
            barx();                                   // all waves: tile kt staged

            const unsigned short* KL = &kv[kt & 1][frag];
            const unsigned short* VL = &kv[kt & 1][2048 + frag];
            bf16x8 kb0 = *(const bf16x8*)(KL);
            bf16x8 kb1 = *(const bf16x8*)(KL + 512);
            bf16x8 kb2 = *(const bf16x8*)(KL + 1024);
            bf16x8 kb3 = *(const bf16x8*)(KL + 1536);
            bf16x8 v0 = *(const bf16x8*)(VL);
            bf16x8 v1 = *(const bf16x8*)(VL + 512);
            bf16x8 v2 = *(const bf16x8*)(VL + 1024);
            bf16x8 v3 = *(const bf16x8*)(VL + 1536);

            f32x4 st0 = (f32x4){0.f, 0.f, 0.f, 0.f};
            f32x4 st1 = (f32x4){0.f, 0.f, 0.f, 0.f};
            __builtin_amdgcn_s_setprio(1);
            st0 = __builtin_amdgcn_mfma_f32_16x16x32_bf16(kb0, qf[0], st0, 0, 0, 0);
            st1 = __builtin_amdgcn_mfma_f32_16x16x32_bf16(kb1, qf[1], st1, 0, 0, 0);
            st0 = __builtin_amdgcn_mfma_f32_16x16x32_bf16(kb2, qf[2], st0, 0, 0, 0);
            st1 = __builtin_amdgcn_mfma_f32_16x16x32_bf16(kb3, qf[3], st1, 0, 0, 0);
            __builtin_amdgcn_s_setprio(0);
            f32x4 stv = st0 + st1;

            float p0, p1, p2, p3;
            int doff = kt - s;                        // wave-uniform
            if (doff >= 0) {
                int d16 = doff << 4;
                p0 = (d16 + quad * 4 + 0 <= l15) ? exp2f(stv[0] * k2) : 0.f;
                p1 = (d16 + quad * 4 + 1 <= l15) ? exp2f(stv[1] * k2) : 0.f;
                p2 = (d16 + quad * 4 + 2 <= l15) ? exp2f(stv[2] * k2) : 0.f;
                p3 = (d16 + quad * 4 + 3 <= l15) ? exp2f(stv[3] * k2) : 0.f;
            } else {
                p0 = exp2f(stv[0] * k2); p1 = exp2f(stv[1] * k2);
                p2 = exp2f(stv[2] * k2); p3 = exp2f(stv[3] * k2);
            }
            l_part += (p0 + p1) + (p2 + p3);

            bf16x4 pf;
            pf[0] = (short)f2bf(p0); pf[1] = (short)f2bf(p1);
            pf[2] = (short)f2bf(p2); pf[3] = (short)f2bf(p3);

            __builtin_amdgcn_s_setprio(1);
            o_acc[0] = pv_mfma(pf, VLO(v0), o_acc[0]);
            o_acc[1] = pv_mfma(pf, VHI(v0), o_acc[1]);
            o_acc[2] = pv_mfma(pf, VLO(v1), o_acc[2]);
            o_acc[3] = pv_mfma(pf, VHI(v1), o_acc[3]);
            o_acc[4] = pv_mfma(pf, VLO(v2), o_acc[4]);
            o_acc[5] = pv_mfma(pf, VHI(v2), o_acc[5]);
            o_acc[6] = pv_mfma(pf, VLO(v3), o_acc[6]);
            o_acc[7] = pv_mfma(pf, VHI(v3), o_acc[7]);
            __builtin_amdgcn_s_setprio(0);
            barx();                                   // reads of buf[kt&1] done
        }
        w_vm0();                                      // drain dummy stage
        barx();                                       // buffers clean for next qblock

        float lp = l_part;
        lp += __shfl_xor(lp, 16, 64);
        lp += __shfl_xor(lp, 32, 64);
#pragma unroll
        for (int reg = 0; reg < 4; ++reg) {
            float l = __shfl(lp, quad * 4 + reg, 64);
            float inv = 1.f / l;
            int srow = r0 + quad * 4 + reg;
            unsigned short* op = O + (size_t)(b * S_LEN + srow) * HID + h * HDIM;
#pragma unroll
            for (int ct = 0; ct < 8; ++ct)
                op[ct * 16 + l15] = f2bf(o_acc[ct][reg] * inv);
        }
    };

    run_qblock(q);        // 4q+4 tiles
    run_qblock(31 - q);   // 128-4q tiles  (total 132, every block)

#undef ASTAGE
#undef VLO
#undef VHI
}

// ---------------------------------------------------------------- launch
extern "C" void kernel_launch(void* const* d_in, const int* in_sizes, int n_in,
                              void* d_out, int out_size, void* d_ws, size_t ws_size,
                              hipStream_t stream) {
    (void)in_sizes; (void)n_in; (void)out_size; (void)ws_size;
    const float* x  = (const float*)d_in[0];
    const float* wq = (const float*)d_in[2];
    const float* bq = (const float*)d_in[3];
    const float* wk = (const float*)d_in[4];
    const float* bk = (const float*)d_in[5];
    const float* wv = (const float*)d_in[6];
    const float* bv = (const float*)d_in[7];
    const float* wo = (const float*)d_in[8];
    const float* bo = (const float*)d_in[9];
    float* out = (float*)d_out;

    unsigned short* ws = (unsigned short*)d_ws;
    const size_t WSZ = 4194304;
    unsigned short* wqT = ws;                // [0, 4M)   wqT/wkT/wvT contiguous =
    unsigned short* wkT = ws + WSZ;          // [4M, 8M)  fused [6144][2048] B for QKV
    unsigned short* wvT = ws + 2 * WSZ;      // [8M, 12M)
    unsigned short* woT = ws + 3 * WSZ;      // [12M, 16M)
    unsigned short* xb  = ws + 4 * WSZ;      // [16M, 24M)
    unsigned short* Ab  = ws + 4 * WSZ;      // aliases xb (dead after QKV gemm)
    unsigned short* Qb  = ws + 6 * WSZ;      // [24M, 32M)
    unsigned short* Kb  = ws + 8 * WSZ;      // [32M, 40M)  fragment-packed
    unsigned short* Vb  = ws + 10 * WSZ;     // [40M, 48M)  fragment-packed

    convert_all<<<dim3(32, 32, 12), 256, 0, stream>>>(x, wq, wk, wv, wo,
                                                      xb, wqT, wkT, wvT, woT);
    gemm8q<<<dim3(512), 512, 0, stream>>>(xb, wqT, bq, bk, bv, Qb, Kb, Vb);
    attn_kernel<<<dim3(512), 256, 0, stream>>>(Qb, Kb, Vb, Ab);
    gemmT<0, 2><<<dim3(256), 512, 0, stream>>>(Ab, woT, bo, out);
}